// Round 6
// baseline (582.133 us; speedup 1.0000x reference)
//
#include <hip/hip_runtime.h>
#include <hip/hip_bf16.h>

// GAT 3-layer: N=40000, E=400000 (+self-loops), H=4, HID=64, NCLS=121, F_IN=50.
// Round 6: edge-phase latency hiding. attn121: block-per-node, 4 waves (1 head
// each, 256B/edge gathers), LDS head-mean reduce. attn64: 2 waves/node (2 heads
// each). Residual buffer now bf16. Softmax without max-shift (logits bounded).

#define NNODES 40000
#define MPAD   40064    // 313 * 128
#define NEDGES 400000
#define FIN    50
#define NHEAD  4
#define SCANB  157      // ceil(40000/256)

typedef __attribute__((ext_vector_type(8))) short short8;
typedef __attribute__((ext_vector_type(4))) float float4v;
typedef __attribute__((ext_vector_type(2))) float float2v;
typedef __attribute__((ext_vector_type(2))) unsigned short ushort2v;
typedef __attribute__((ext_vector_type(8))) unsigned short ushort8v;

__device__ inline unsigned short f2bf(float f) {   // round-to-nearest-even bf16
    union { float f; unsigned u; } v; v.f = f;
    unsigned r = v.u + 0x7fff + ((v.u >> 16) & 1);
    return (unsigned short)(r >> 16);
}
__device__ inline float bf2f(unsigned short u) {
    union { unsigned u; float f; } v; v.u = ((unsigned)u) << 16; return v.f;
}
__device__ inline float lrelu(float x) { return x >= 0.f ? x : 0.2f * x; }

// ---------------------------------------------------------------- CSR build
__global__ void hist_kernel(const int* __restrict__ dst, int* __restrict__ counts, int E) {
    int i = blockIdx.x * blockDim.x + threadIdx.x;
    if (i < E) atomicAdd(&counts[dst[i]], 1);
}

__global__ __launch_bounds__(256) void scan_local(const int* __restrict__ counts,
                                                  int* __restrict__ offsets,
                                                  int* __restrict__ partials) {
    __shared__ int sh[256];
    int b = blockIdx.x, t = threadIdx.x, i = b * 256 + t;
    int v = (i < NNODES) ? counts[i] : 0;
    sh[t] = v;
    __syncthreads();
    #pragma unroll
    for (int off = 1; off < 256; off <<= 1) {
        int u = (t >= off) ? sh[t - off] : 0;
        __syncthreads();
        sh[t] += u;
        __syncthreads();
    }
    if (i < NNODES) offsets[i] = sh[t] - v;     // local exclusive
    if (t == 255) partials[b] = sh[255];
}

__global__ __launch_bounds__(256) void scan_partials(int* __restrict__ partials,
                                                     int* __restrict__ pexcl) {
    __shared__ int sh[256];
    int t = threadIdx.x;
    int v = (t < SCANB) ? partials[t] : 0;
    sh[t] = v;
    __syncthreads();
    #pragma unroll
    for (int off = 1; off < 256; off <<= 1) {
        int u = (t >= off) ? sh[t - off] : 0;
        __syncthreads();
        sh[t] += u;
        __syncthreads();
    }
    pexcl[t] = sh[t] - v;
}

__global__ __launch_bounds__(256) void scan_carry(int* __restrict__ offsets,
                                                  const int* __restrict__ pexcl) {
    int b = blockIdx.x, i = b * 256 + threadIdx.x;
    if (i < NNODES) offsets[i] += pexcl[b];
    if (i == 0) offsets[NNODES] = NEDGES;
}

__global__ void scatter_kernel(const int* __restrict__ src, const int* __restrict__ dst,
                               const int* __restrict__ offsets, int* __restrict__ cursor,
                               int* __restrict__ csr_src, int* __restrict__ csr_dst, int E) {
    int i = blockIdx.x * blockDim.x + threadIdx.x;
    if (i < E) {
        int d = dst[i];
        int pos = offsets[d] + atomicAdd(&cursor[d], 1);
        csr_src[pos] = src[i];
        csr_dst[pos] = d;
    }
}

// per-edge softmax numerators for all 4 heads (no max subtraction; logits bounded)
__global__ void edge_p(const float* __restrict__ als, const float* __restrict__ ald,
                       const int* __restrict__ csr_src, const int* __restrict__ csr_dst,
                       float* __restrict__ p4, int E) {
    int j = blockIdx.x * blockDim.x + threadIdx.x;
    if (j >= E) return;
    int s = csr_src[j], d = csr_dst[j];
    float4v a = *(const float4v*)&als[s * 4];
    float4v b = *(const float4v*)&ald[d * 4];
    float4v p;
    p.x = __expf(lrelu(a.x + b.x)); p.y = __expf(lrelu(a.y + b.y));
    p.z = __expf(lrelu(a.z + b.z)); p.w = __expf(lrelu(a.w + b.w));
    *(float4v*)&p4[(size_t)j * 4] = p;
}

// ---------------------------------------------------------------- converts
__global__ void convert_x(const float* __restrict__ x, short* __restrict__ xb) {
    int i = blockIdx.x * blockDim.x + threadIdx.x;   // over MPAD*64
    if (i >= MPAD * 64) return;
    int r = i >> 6, k = i & 63;
    float v = (r < NNODES && k < FIN) ? x[r * FIN + k] : 0.f;
    xb[i] = f2bf(v);
}

// fused: w1t[256][64], wr1t[256][64], w2t[256][256], wr2t[256][256]
__global__ void convert_pack1(const float* __restrict__ W1, const float* __restrict__ Wr1,
                              const float* __restrict__ W2, const float* __restrict__ Wr2,
                              short* __restrict__ w1t, short* __restrict__ wr1t,
                              short* __restrict__ w2t, short* __restrict__ wr2t) {
    int i = blockIdx.x * blockDim.x + threadIdx.x;
    if (i < 32768) {                      // w1t / wr1t: Kpad=64, N=256, K=50
        const float* W = (i < 16384) ? W1 : Wr1;
        short* T = (i < 16384) ? w1t : wr1t;
        int j = i & 16383;
        int n = j >> 6, k = j & 63;
        T[j] = f2bf((k < FIN) ? W[k * 256 + n] : 0.f);
    } else if (i < 163840) {              // w2t / wr2t: Kpad=256, N=256
        int j = (i - 32768) & 65535;
        const float* W = (i < 98304) ? W2 : Wr2;
        short* T = (i < 98304) ? w2t : wr2t;
        int n = j >> 8, k = j & 255;
        T[j] = f2bf(W[k * 256 + n]);
    }
}

// fused: w3t[512][256] (head-padded cols), wr3t[128][256], a3s/a3d pads [4][128]
__global__ void convert_pack2(const float* __restrict__ W3, const float* __restrict__ Wr3,
                              const float* __restrict__ a3s, const float* __restrict__ a3d,
                              short* __restrict__ w3t, short* __restrict__ wr3t,
                              float* __restrict__ a3sp, float* __restrict__ a3dp) {
    int i = blockIdx.x * blockDim.x + threadIdx.x;
    if (i < 131072) {                     // w3t: col j = h*128+c <- W3[k][h*121+c]
        int j = i >> 8, k = i & 255;
        int h = j >> 7, c = j & 127;
        w3t[i] = f2bf((c < 121) ? W3[k * 484 + h * 121 + c] : 0.f);
    } else if (i < 163840) {              // wr3t: [128][256], N=121
        int j = i - 131072;
        int n = j >> 8, k = j & 255;
        wr3t[j] = f2bf((n < 121) ? Wr3[k * 121 + n] : 0.f);
    } else if (i < 164864) {              // a3 pads
        int j = i - 163840;
        int which = j >> 9; int jj = j & 511;
        int h = jj >> 7, c = jj & 127;
        float v = (c < 121) ? (which ? a3d[h * 121 + c] : a3s[h * 121 + c]) : 0.f;
        (which ? a3dp : a3sp)[jj] = v;
    }
}

// ---------------------------------------------------------------- MFMA GEMM
template<int BF16OUT>
__global__ __launch_bounds__(256) void mfma_gemm(const short* __restrict__ A,
                                                 const short* __restrict__ Bt,
                                                 const float* __restrict__ bias,
                                                 float* __restrict__ C,
                                                 unsigned short* __restrict__ Cb,
                                                 int Kp, int Nreal, int ldC) {
    __shared__ __align__(16) short As[4096];
    const int tid = threadIdx.x;
    const int l   = tid & 63;
    const int w   = tid >> 6;
    const int wm  = w >> 1, wn = w & 1;
    const int row0 = blockIdx.y * 128;
    const int col0 = blockIdx.x * 128;
    const int lrow = l & 15;
    const int lq   = l >> 4;
    const int sr = (tid >> 6) * 16 + (tid & 15);
    const int sk = ((tid >> 4) & 3) * 8;

    float4v acc[4][4] = {};

    for (int k0 = 0; k0 < Kp; k0 += 32) {
        short8 a0 = *(const short8*)&A[(size_t)(row0 + sr) * Kp + k0 + sk];
        short8 a1 = *(const short8*)&A[(size_t)(row0 + 64 + sr) * Kp + k0 + sk];
        short8 bfrag[4];
        #pragma unroll
        for (int ct = 0; ct < 4; ++ct) {
            int col = col0 + wn * 64 + ct * 16 + lrow;
            bfrag[ct] = *(const short8*)&Bt[(size_t)col * Kp + k0 + lq * 8];
        }
        __syncthreads();
        *(short8*)&As[tid * 8] = a0;
        *(short8*)&As[(tid + 256) * 8] = a1;
        __syncthreads();
        #pragma unroll
        for (int rt = 0; rt < 4; ++rt) {
            short8 afrag = *(const short8*)&As[(wm * 4 + rt) * 512 + l * 8];
            #pragma unroll
            for (int ct = 0; ct < 4; ++ct)
                acc[rt][ct] = __builtin_amdgcn_mfma_f32_16x16x32_bf16(afrag, bfrag[ct],
                                                                      acc[rt][ct], 0, 0, 0);
        }
    }

    #pragma unroll
    for (int ct = 0; ct < 4; ++ct) {
        int col = col0 + wn * 64 + ct * 16 + lrow;
        if (col >= Nreal) continue;
        float bv = bias ? bias[col] : 0.f;
        #pragma unroll
        for (int rt = 0; rt < 4; ++rt) {
            int rbase = row0 + wm * 64 + rt * 16 + lq * 4;
            #pragma unroll
            for (int i = 0; i < 4; ++i) {
                int r = rbase + i;
                if (r < NNODES) {
                    float v = acc[rt][ct][i] + bv;
                    if (BF16OUT) Cb[(size_t)r * ldC + col] = f2bf(v);
                    else         C [(size_t)r * ldC + col] = v;
                }
            }
        }
    }
}

// --------------------------------------------------- attention logits (bf16 feat)
__global__ __launch_bounds__(256) void al_kernel(const unsigned short* __restrict__ featb,
                                                 const float* __restrict__ a_s,
                                                 const float* __restrict__ a_d,
                                                 float* __restrict__ als,
                                                 float* __restrict__ ald, int C, int ldF) {
    int n = blockIdx.x;
    int h = threadIdx.x >> 6;
    int l = threadIdx.x & 63;
    float vs = 0.f, vd = 0.f;
    for (int c = l; c < C; c += 64) {
        float f = bf2f(featb[(size_t)n * ldF + h * C + c]);
        vs += f * a_s[h * C + c];
        vd += f * a_d[h * C + c];
    }
    #pragma unroll
    for (int off = 32; off > 0; off >>= 1) {
        vs += __shfl_down(vs, off, 64);
        vd += __shfl_down(vd, off, 64);
    }
    if (l == 0) { als[n * NHEAD + h] = vs; ald[n * NHEAD + h] = vd; }
}

// --------------------------------------------------- attn layers 1-2 (C=64, concat)
// 2 waves per node, each wave = 2 heads (128 ch), lane = 2 channels (4B gather).
__global__ __launch_bounds__(256) void attn64_kernel(const unsigned short* __restrict__ featb,
                                                     const float* __restrict__ als,
                                                     const float* __restrict__ ald,
                                                     const int* __restrict__ offsets,
                                                     const int* __restrict__ csr,
                                                     const float* __restrict__ p4,
                                                     const unsigned short* __restrict__ Rb,
                                                     unsigned short* __restrict__ outb) {
    int widx = threadIdx.x >> 6;
    int n = blockIdx.x * 2 + (widx >> 1);
    int w = widx & 1;
    int l = threadIdx.x & 63;
    int h = 2 * w + (l >> 5);
    int beg = offsets[n], end = offsets[n + 1];

    float p0 = __expf(lrelu(als[n * 4 + h] + ald[n * 4 + h]));
    float s = p0;
    size_t base = (size_t)n * 256 + w * 128 + 2 * l;
    float a0, a1;
    {
        ushort2v f = *(const ushort2v*)&featb[base];
        a0 = p0 * bf2f(f.x); a1 = p0 * bf2f(f.y);
    }
    #pragma unroll 8
    for (int j = beg; j < end; ++j) {
        int sn = csr[j];
        float p = p4[(size_t)j * 4 + h];
        s += p;
        ushort2v f = *(const ushort2v*)&featb[(size_t)sn * 256 + w * 128 + 2 * l];
        a0 += p * bf2f(f.x); a1 += p * bf2f(f.y);
    }
    float inv = 1.f / s;
    ushort2v r = *(const ushort2v*)&Rb[base];
    ushort2v o;
    o.x = f2bf(fmaxf(bf2f(r.x) + a0 * inv, 0.f));
    o.y = f2bf(fmaxf(bf2f(r.y) + a1 * inv, 0.f));
    *(ushort2v*)&outb[base] = o;
}

// --------------------------------------------------- attn layer 3 (C=121 pad 128, mean)
// block per node: 4 waves, wave h handles head h (128 ch, 2/lane); LDS reduce.
__global__ __launch_bounds__(256) void attn121_kernel(const unsigned short* __restrict__ featb,
                                                      const float* __restrict__ als,
                                                      const float* __restrict__ ald,
                                                      const int* __restrict__ offsets,
                                                      const int* __restrict__ csr,
                                                      const float* __restrict__ p4,
                                                      float* __restrict__ out) {
    __shared__ float sh[4][128];
    int n = blockIdx.x;
    int h = threadIdx.x >> 6;
    int l = threadIdx.x & 63;
    int beg = offsets[n], end = offsets[n + 1];

    float p0 = __expf(lrelu(als[n * 4 + h] + ald[n * 4 + h]));
    float s = p0;
    size_t base = (size_t)n * 512 + h * 128 + 2 * l;
    float a0, a1;
    {
        ushort2v f = *(const ushort2v*)&featb[base];
        a0 = p0 * bf2f(f.x); a1 = p0 * bf2f(f.y);
    }
    #pragma unroll 8
    for (int j = beg; j < end; ++j) {
        int sn = csr[j];
        float p = p4[(size_t)j * 4 + h];
        s += p;
        ushort2v f = *(const ushort2v*)&featb[(size_t)sn * 512 + h * 128 + 2 * l];
        a0 += p * bf2f(f.x); a1 += p * bf2f(f.y);
    }
    float inv = 0.25f / s;                 // mean over 4 heads
    float2v t; t.x = a0 * inv; t.y = a1 * inv;
    *(float2v*)&sh[h][2 * l] = t;
    __syncthreads();
    int c = threadIdx.x;
    if (c < 121) out[(size_t)n * 121 + c] += sh[0][c] + sh[1][c] + sh[2][c] + sh[3][c];
}

// ---------------------------------------------------------------- launch
extern "C" void kernel_launch(void* const* d_in, const int* in_sizes, int n_in,
                              void* d_out, int out_size, void* d_ws, size_t ws_size,
                              hipStream_t stream) {
    const float* x   = (const float*)d_in[0];
    const int* ei    = (const int*)d_in[1];
    const float* W1  = (const float*)d_in[2];
    const float* a1s = (const float*)d_in[3];
    const float* a1d = (const float*)d_in[4];
    const float* Wr1 = (const float*)d_in[5];
    const float* b1  = (const float*)d_in[6];
    const float* W2  = (const float*)d_in[7];
    const float* a2s = (const float*)d_in[8];
    const float* a2d = (const float*)d_in[9];
    const float* Wr2 = (const float*)d_in[10];
    const float* b2  = (const float*)d_in[11];
    const float* W3  = (const float*)d_in[12];
    const float* a3s = (const float*)d_in[13];
    const float* a3d = (const float*)d_in[14];
    const float* Wr3 = (const float*)d_in[15];
    const float* b3  = (const float*)d_in[16];
    float* out = (float*)d_out;

    const int* e_src = ei;
    const int* e_dst = ei + NEDGES;

    char* ws = (char*)d_ws;
    size_t off = 0;
    auto carve = [&](size_t bytes) { void* p = ws + off; off += (bytes + 255) & ~255ull; return p; };
    unsigned short* Fb = (unsigned short*)carve((size_t)MPAD * 512 * 2);
    unsigned short* Rb = (unsigned short*)carve((size_t)MPAD * 256 * 2);  // bf16 residual
    short* Hb   = (short*)carve((size_t)MPAD * 256 * 2);
    short* xb   = (short*)carve((size_t)MPAD * 64 * 2);
    short* w1t  = (short*)carve((size_t)256 * 64 * 2);
    short* wr1t = (short*)carve((size_t)256 * 64 * 2);
    short* w2t  = (short*)carve((size_t)256 * 256 * 2);
    short* wr2t = (short*)carve((size_t)256 * 256 * 2);
    short* w3t  = (short*)carve((size_t)512 * 256 * 2);
    short* wr3t = (short*)carve((size_t)128 * 256 * 2);
    float* a3sp = (float*)carve(512 * 4);
    float* a3dp = (float*)carve(512 * 4);
    float* als  = (float*)carve((size_t)NNODES * NHEAD * 4);
    float* ald  = (float*)carve((size_t)NNODES * NHEAD * 4);
    float* p4   = (float*)carve((size_t)NEDGES * 4 * 4);
    int* csr_src = (int*)carve((size_t)NEDGES * 4);
    int* csr_dst = (int*)carve((size_t)NEDGES * 4);
    int* offsets = (int*)carve(((size_t)NNODES + 4) * 4);
    int* cursor  = (int*)carve((size_t)NNODES * 4);
    int* partials = (int*)carve(256 * 4);
    int* pexcl    = (int*)carve(256 * 4);

    const int EB = (NEDGES + 255) / 256;
    dim3 blk(256);

    // conversions (3 launches)
    convert_x<<<(MPAD * 64 + 255) / 256, blk, 0, stream>>>(x, xb);
    convert_pack1<<<(163840 + 255) / 256, blk, 0, stream>>>(W1, Wr1, W2, Wr2, w1t, wr1t, w2t, wr2t);
    convert_pack2<<<(164864 + 255) / 256, blk, 0, stream>>>(W3, Wr3, a3s, a3d, w3t, wr3t, a3sp, a3dp);

    // CSR by dst (parallel scan)
    hipMemsetAsync(cursor, 0, NNODES * 4, stream);
    hist_kernel<<<EB, blk, 0, stream>>>(e_dst, cursor, NEDGES);
    scan_local<<<SCANB, blk, 0, stream>>>(cursor, offsets, partials);
    scan_partials<<<1, blk, 0, stream>>>(partials, pexcl);
    scan_carry<<<SCANB, blk, 0, stream>>>(offsets, pexcl);
    hipMemsetAsync(cursor, 0, NNODES * 4, stream);
    scatter_kernel<<<EB, blk, 0, stream>>>(e_src, e_dst, offsets, cursor, csr_src, csr_dst, NEDGES);

    // layer 1
    mfma_gemm<1><<<dim3(2, 313), blk, 0, stream>>>(xb, w1t, nullptr, nullptr, (unsigned short*)Fb, 64, 256, 256);
    mfma_gemm<1><<<dim3(2, 313), blk, 0, stream>>>(xb, wr1t, b1, nullptr, Rb, 64, 256, 256);
    al_kernel<<<NNODES, blk, 0, stream>>>(Fb, a1s, a1d, als, ald, 64, 256);
    edge_p<<<EB, blk, 0, stream>>>(als, ald, csr_src, csr_dst, p4, NEDGES);
    attn64_kernel<<<NNODES / 2, blk, 0, stream>>>(Fb, als, ald, offsets, csr_src, p4, Rb, (unsigned short*)Hb);

    // layer 2
    mfma_gemm<1><<<dim3(2, 313), blk, 0, stream>>>(Hb, w2t, nullptr, nullptr, (unsigned short*)Fb, 256, 256, 256);
    mfma_gemm<1><<<dim3(2, 313), blk, 0, stream>>>(Hb, wr2t, b2, nullptr, Rb, 256, 256, 256);
    al_kernel<<<NNODES, blk, 0, stream>>>(Fb, a2s, a2d, als, ald, 64, 256);
    edge_p<<<EB, blk, 0, stream>>>(als, ald, csr_src, csr_dst, p4, NEDGES);
    attn64_kernel<<<NNODES / 2, blk, 0, stream>>>(Fb, als, ald, offsets, csr_src, p4, Rb, (unsigned short*)Hb);

    // layer 3
    mfma_gemm<1><<<dim3(4, 313), blk, 0, stream>>>(Hb, w3t, nullptr, nullptr, (unsigned short*)Fb, 256, 512, 512);
    mfma_gemm<0><<<dim3(1, 313), blk, 0, stream>>>(Hb, wr3t, b3, out, nullptr, 256, 121, 121);
    al_kernel<<<NNODES, blk, 0, stream>>>(Fb, a3sp, a3dp, als, ald, 128, 512);
    edge_p<<<EB, blk, 0, stream>>>(als, ald, csr_src, csr_dst, p4, NEDGES);
    attn121_kernel<<<NNODES, blk, 0, stream>>>(Fb, als, ald, offsets, csr_src, p4, out);
}

// Round 7
// 514.609 us; speedup vs baseline: 1.1312x; 1.1312x over previous
//
#include <hip/hip_runtime.h>
#include <hip/hip_bf16.h>

// GAT 3-layer: N=40000, E=400000 (+self-loops), H=4, HID=64, NCLS=121, F_IN=50.
// Round 7: revert attn to round-5 shape (wave/node, wide gathers). Fuse W|Wr
// GEMMs (one launch/layer) and fold attention-logit dots (al_s/al_d) into the
// GEMM epilogue (16-lane reduce + atomicAdd; cols of a wave are single-head).
// Scatter mutates offsets (beg = offs[n-1]). 21 dispatches total.

#define NNODES 40000
#define MPAD   40064    // 313 * 128
#define NEDGES 400000
#define FIN    50
#define NHEAD  4
#define SCANB  157      // ceil(40000/256)

typedef __attribute__((ext_vector_type(8))) short short8;
typedef __attribute__((ext_vector_type(4))) float float4v;
typedef __attribute__((ext_vector_type(4))) unsigned short ushort4v;
typedef __attribute__((ext_vector_type(8))) unsigned short ushort8v;

__device__ inline unsigned short f2bf(float f) {   // round-to-nearest-even bf16
    union { float f; unsigned u; } v; v.f = f;
    unsigned r = v.u + 0x7fff + ((v.u >> 16) & 1);
    return (unsigned short)(r >> 16);
}
__device__ inline float bf2f(unsigned short u) {
    union { unsigned u; float f; } v; v.u = ((unsigned)u) << 16; return v.f;
}
__device__ inline float lrelu(float x) { return x >= 0.f ? x : 0.2f * x; }

// ---------------------------------------------------------------- CSR build
__global__ void hist_kernel(const int* __restrict__ dst, int* __restrict__ counts, int E) {
    int i = blockIdx.x * blockDim.x + threadIdx.x;
    if (i < E) atomicAdd(&counts[dst[i]], 1);
}

__global__ __launch_bounds__(256) void scan_local(const int* __restrict__ counts,
                                                  int* __restrict__ offsets,
                                                  int* __restrict__ partials) {
    __shared__ int sh[256];
    int b = blockIdx.x, t = threadIdx.x, i = b * 256 + t;
    int v = (i < NNODES) ? counts[i] : 0;
    sh[t] = v;
    __syncthreads();
    #pragma unroll
    for (int off = 1; off < 256; off <<= 1) {
        int u = (t >= off) ? sh[t - off] : 0;
        __syncthreads();
        sh[t] += u;
        __syncthreads();
    }
    if (i < NNODES) offsets[i] = sh[t] - v;     // local exclusive
    if (t == 255) partials[b] = sh[255];
}

__global__ __launch_bounds__(256) void scan_partials(int* __restrict__ partials,
                                                     int* __restrict__ pexcl) {
    __shared__ int sh[256];
    int t = threadIdx.x;
    int v = (t < SCANB) ? partials[t] : 0;
    sh[t] = v;
    __syncthreads();
    #pragma unroll
    for (int off = 1; off < 256; off <<= 1) {
        int u = (t >= off) ? sh[t - off] : 0;
        __syncthreads();
        sh[t] += u;
        __syncthreads();
    }
    pexcl[t] = sh[t] - v;
}

__global__ __launch_bounds__(256) void scan_carry(int* __restrict__ offsets,
                                                  const int* __restrict__ pexcl) {
    int b = blockIdx.x, i = b * 256 + threadIdx.x;
    if (i < NNODES) offsets[i] += pexcl[b];
}

// mutates offsets: after this, offsets[d] = end(d); beg(d) = offsets[d-1] (0 for d=0)
__global__ void scatter_kernel(const int* __restrict__ src, const int* __restrict__ dst,
                               int* __restrict__ offsets,
                               int* __restrict__ csr_src, int* __restrict__ csr_dst, int E) {
    int i = blockIdx.x * blockDim.x + threadIdx.x;
    if (i < E) {
        int d = dst[i];
        int pos = atomicAdd(&offsets[d], 1);
        csr_src[pos] = src[i];
        csr_dst[pos] = d;
    }
}

// per-edge softmax numerators for all 4 heads (no max subtraction; logits bounded)
__global__ void edge_p(const float* __restrict__ als, const float* __restrict__ ald,
                       const int* __restrict__ csr_src, const int* __restrict__ csr_dst,
                       float* __restrict__ p4, int E) {
    int j = blockIdx.x * blockDim.x + threadIdx.x;
    if (j >= E) return;
    int s = csr_src[j], d = csr_dst[j];
    float4v a = *(const float4v*)&als[s * 4];
    float4v b = *(const float4v*)&ald[d * 4];
    float4v p;
    p.x = __expf(lrelu(a.x + b.x)); p.y = __expf(lrelu(a.y + b.y));
    p.z = __expf(lrelu(a.z + b.z)); p.w = __expf(lrelu(a.w + b.w));
    *(float4v*)&p4[(size_t)j * 4] = p;
}

// ---------------------------------------------------------------- converts
__global__ void convert_x(const float* __restrict__ x, short* __restrict__ xb) {
    int i = blockIdx.x * blockDim.x + threadIdx.x;   // over MPAD*64
    if (i >= MPAD * 64) return;
    int r = i >> 6, k = i & 63;
    float v = (r < NNODES && k < FIN) ? x[r * FIN + k] : 0.f;
    xb[i] = f2bf(v);
}

// fused: w1t[256][64]|wr1t[256][64] (combined), w2t[256][256]|wr2t[256][256]
__global__ void convert_pack1(const float* __restrict__ W1, const float* __restrict__ Wr1,
                              const float* __restrict__ W2, const float* __restrict__ Wr2,
                              short* __restrict__ wc1, short* __restrict__ wc2) {
    int i = blockIdx.x * blockDim.x + threadIdx.x;
    if (i < 32768) {                      // wc1: rows 0-255 = W1^T, 256-511 = Wr1^T
        const float* W = (i < 16384) ? W1 : Wr1;
        int j = i & 16383;
        int n = j >> 6, k = j & 63;
        wc1[i] = f2bf((k < FIN) ? W[k * 256 + n] : 0.f);
    } else if (i < 163840) {              // wc2: rows 0-255 = W2^T, 256-511 = Wr2^T
        int j = (i - 32768) & 65535;
        const float* W = (i < 98304) ? W2 : Wr2;
        int n = j >> 8, k = j & 255;
        wc2[(i - 32768)] = f2bf(W[k * 256 + n]);
    }
}

// fused: wc3 rows 0-511 = W3^T head-padded, rows 512-639 = Wr3^T; a3 pads [4][128]
__global__ void convert_pack2(const float* __restrict__ W3, const float* __restrict__ Wr3,
                              const float* __restrict__ a3s, const float* __restrict__ a3d,
                              short* __restrict__ wc3,
                              float* __restrict__ a3sp, float* __restrict__ a3dp) {
    int i = blockIdx.x * blockDim.x + threadIdx.x;
    if (i < 131072) {                     // w3t: row j = h*128+c <- W3[k][h*121+c]
        int j = i >> 8, k = i & 255;
        int h = j >> 7, c = j & 127;
        wc3[i] = f2bf((c < 121) ? W3[k * 484 + h * 121 + c] : 0.f);
    } else if (i < 163840) {              // wr3t rows: [128][256], N=121
        int j = i - 131072;
        int n = j >> 8, k = j & 255;
        wc3[131072 + j] = f2bf((n < 121) ? Wr3[k * 121 + n] : 0.f);
    } else if (i < 164864) {              // a3 pads
        int j = i - 163840;
        int which = j >> 9; int jj = j & 511;
        int h = jj >> 7, c = jj & 127;
        float v = (c < 121) ? (which ? a3d[h * 121 + c] : a3s[h * 121 + c]) : 0.f;
        (which ? a3dp : a3sp)[jj] = v;
    }
}

// ---------------------------------------------------------------- fused MFMA GEMM
// MODE 0 (layers 1-2): N=512 = [feat 256 | residual 256], both bf16 out, ld 256.
// MODE 1 (layer 3):    N=640 = [feat 512 | out 121(pad128)], feat bf16 ld 512, out fp32.
// W-part epilogue also reduces al_s/al_d dots (cols of one wave = single head)
// into als/ald via atomicAdd (als/ald pre-zeroed).
template<int MODE>
__global__ __launch_bounds__(256) void mfma_gemm_fused(const short* __restrict__ A,
                                                       const short* __restrict__ Bt,
                                                       const float* __restrict__ bias,
                                                       const float* __restrict__ asv,
                                                       const float* __restrict__ adv,
                                                       unsigned short* __restrict__ Fb,
                                                       unsigned short* __restrict__ Rb,
                                                       float* __restrict__ out,
                                                       float* __restrict__ als,
                                                       float* __restrict__ ald,
                                                       int Kp) {
    const int NW = MODE ? 512 : 256;
    __shared__ __align__(16) short As[4096];
    const int tid = threadIdx.x;
    const int l   = tid & 63;
    const int w   = tid >> 6;
    const int wm  = w >> 1, wn = w & 1;
    const int row0 = blockIdx.y * 128;
    const int col0 = blockIdx.x * 128;
    const int lrow = l & 15;
    const int lq   = l >> 4;
    const int sr = (tid >> 6) * 16 + (tid & 15);
    const int sk = ((tid >> 4) & 3) * 8;

    float4v acc[4][4] = {};

    for (int k0 = 0; k0 < Kp; k0 += 32) {
        short8 a0 = *(const short8*)&A[(size_t)(row0 + sr) * Kp + k0 + sk];
        short8 a1 = *(const short8*)&A[(size_t)(row0 + 64 + sr) * Kp + k0 + sk];
        short8 bfrag[4];
        #pragma unroll
        for (int ct = 0; ct < 4; ++ct) {
            int col = col0 + wn * 64 + ct * 16 + lrow;
            bfrag[ct] = *(const short8*)&Bt[(size_t)col * Kp + k0 + lq * 8];
        }
        __syncthreads();
        *(short8*)&As[tid * 8] = a0;
        *(short8*)&As[(tid + 256) * 8] = a1;
        __syncthreads();
        #pragma unroll
        for (int rt = 0; rt < 4; ++rt) {
            short8 afrag = *(const short8*)&As[(wm * 4 + rt) * 512 + l * 8];
            #pragma unroll
            for (int ct = 0; ct < 4; ++ct)
                acc[rt][ct] = __builtin_amdgcn_mfma_f32_16x16x32_bf16(afrag, bfrag[ct],
                                                                      acc[rt][ct], 0, 0, 0);
        }
    }

    const int colbase = col0 + wn * 64;           // this wave's 64-col span start
    const bool isW = colbase < NW;

    // ---- stores
    #pragma unroll
    for (int ct = 0; ct < 4; ++ct) {
        int col = colbase + ct * 16 + lrow;
        #pragma unroll
        for (int rt = 0; rt < 4; ++rt) {
            int rbase = row0 + wm * 64 + rt * 16 + lq * 4;
            #pragma unroll
            for (int i = 0; i < 4; ++i) {
                int r = rbase + i;
                if (r >= NNODES) continue;
                float v = acc[rt][ct][i];
                if (MODE == 0) {
                    if (col < 256) Fb[(size_t)r * 256 + col] = f2bf(v);
                    else           Rb[(size_t)r * 256 + col - 256] = f2bf(v + bias[col - 256]);
                } else {
                    if (col < 512) Fb[(size_t)r * 512 + col] = f2bf(v);
                    else { int c = col - 512; if (c < 121) out[(size_t)r * 121 + c] = v + bias[c]; }
                }
            }
        }
    }

    // ---- al_s / al_d reduction (W-part only; wave's cols are one head)
    if (isW) {
        const int head = (colbase * NHEAD) / NW;
        float as_c[4], ad_c[4];
        #pragma unroll
        for (int ct = 0; ct < 4; ++ct) {
            int col = colbase + ct * 16 + lrow;
            as_c[ct] = asv[col];
            ad_c[ct] = adv[col];
        }
        #pragma unroll
        for (int rt = 0; rt < 4; ++rt) {
            #pragma unroll
            for (int i = 0; i < 4; ++i) {
                int r = row0 + wm * 64 + rt * 16 + lq * 4 + i;
                float fs = 0.f, fd = 0.f;
                #pragma unroll
                for (int ct = 0; ct < 4; ++ct) {
                    float v = acc[rt][ct][i];
                    fs += v * as_c[ct];
                    fd += v * ad_c[ct];
                }
                #pragma unroll
                for (int o2 = 8; o2; o2 >>= 1) {
                    fs += __shfl_xor(fs, o2, 16);
                    fd += __shfl_xor(fd, o2, 16);
                }
                if (lrow == 0 && r < NNODES) {
                    atomicAdd(&als[r * 4 + head], fs);
                    atomicAdd(&ald[r * 4 + head], fd);
                }
            }
        }
    }
}

// --------------------------------------------------- attn layers 1-2 (C=64, concat)
// wave per node (4 heads in 16-lane groups), lane = 4 channels (8B gathers).
__global__ __launch_bounds__(256) void attn64_kernel(const unsigned short* __restrict__ featb,
                                                     const float* __restrict__ als,
                                                     const float* __restrict__ ald,
                                                     const int* __restrict__ offs,
                                                     const int* __restrict__ csr,
                                                     const float* __restrict__ p4,
                                                     const unsigned short* __restrict__ Rb,
                                                     unsigned short* __restrict__ outb) {
    int n = blockIdx.x * 4 + (threadIdx.x >> 6);
    int l = threadIdx.x & 63;
    int h = l >> 4;
    int beg = n ? offs[n - 1] : 0;
    int end = offs[n];

    float p0 = __expf(lrelu(als[n * 4 + h] + ald[n * 4 + h]));   // self-loop
    float s = p0;
    float a0, a1, a2, a3;
    {
        ushort4v f = *(const ushort4v*)&featb[(size_t)n * 256 + 4 * l];
        a0 = p0 * bf2f(f.x); a1 = p0 * bf2f(f.y); a2 = p0 * bf2f(f.z); a3 = p0 * bf2f(f.w);
    }
    #pragma unroll 8
    for (int j = beg; j < end; ++j) {
        int sn = csr[j];
        float p = p4[(size_t)j * 4 + h];
        s += p;
        ushort4v f = *(const ushort4v*)&featb[(size_t)sn * 256 + 4 * l];
        a0 += p * bf2f(f.x); a1 += p * bf2f(f.y); a2 += p * bf2f(f.z); a3 += p * bf2f(f.w);
    }
    float inv = 1.f / s;
    ushort4v r = *(const ushort4v*)&Rb[(size_t)n * 256 + 4 * l];
    ushort4v o;
    o.x = f2bf(fmaxf(bf2f(r.x) + a0 * inv, 0.f));
    o.y = f2bf(fmaxf(bf2f(r.y) + a1 * inv, 0.f));
    o.z = f2bf(fmaxf(bf2f(r.z) + a2 * inv, 0.f));
    o.w = f2bf(fmaxf(bf2f(r.w) + a3 * inv, 0.f));
    *(ushort4v*)&outb[(size_t)n * 256 + 4 * l] = o;
}

// --------------------------------------------------- attn layer 3 (C=121 pad 128, mean)
// wave per node, lane = 8 channels (16B gathers); head-mean via shfl_xor.
__global__ __launch_bounds__(256) void attn121_kernel(const unsigned short* __restrict__ featb,
                                                      const float* __restrict__ als,
                                                      const float* __restrict__ ald,
                                                      const int* __restrict__ offs,
                                                      const int* __restrict__ csr,
                                                      const float* __restrict__ p4,
                                                      float* __restrict__ out) {
    int n = blockIdx.x * 4 + (threadIdx.x >> 6);
    int l = threadIdx.x & 63;
    int h = l >> 4;
    int beg = n ? offs[n - 1] : 0;
    int end = offs[n];

    float p0 = __expf(lrelu(als[n * 4 + h] + ald[n * 4 + h]));
    float s = p0;
    float a[8];
    {
        ushort8v f = *(const ushort8v*)&featb[(size_t)n * 512 + 8 * l];
        #pragma unroll
        for (int i = 0; i < 8; ++i) a[i] = p0 * bf2f(f[i]);
    }
    #pragma unroll 4
    for (int j = beg; j < end; ++j) {
        int sn = csr[j];
        float p = p4[(size_t)j * 4 + h];
        s += p;
        ushort8v f = *(const ushort8v*)&featb[(size_t)sn * 512 + 8 * l];
        #pragma unroll
        for (int i = 0; i < 8; ++i) a[i] += p * bf2f(f[i]);
    }
    float inv = 0.25f / s;                 // mean over heads
    #pragma unroll
    for (int i = 0; i < 8; ++i) {
        a[i] *= inv;
        a[i] += __shfl_xor(a[i], 16, 64);  // sum the 4 head groups
        a[i] += __shfl_xor(a[i], 32, 64);
    }
    if (l < 16) {
        #pragma unroll
        for (int i = 0; i < 8; ++i) {
            int c = 8 * l + i;
            if (c < 121) out[(size_t)n * 121 + c] += a[i];
        }
    }
}

// ---------------------------------------------------------------- launch
extern "C" void kernel_launch(void* const* d_in, const int* in_sizes, int n_in,
                              void* d_out, int out_size, void* d_ws, size_t ws_size,
                              hipStream_t stream) {
    const float* x   = (const float*)d_in[0];
    const int* ei    = (const int*)d_in[1];
    const float* W1  = (const float*)d_in[2];
    const float* a1s = (const float*)d_in[3];
    const float* a1d = (const float*)d_in[4];
    const float* Wr1 = (const float*)d_in[5];
    const float* b1  = (const float*)d_in[6];
    const float* W2  = (const float*)d_in[7];
    const float* a2s = (const float*)d_in[8];
    const float* a2d = (const float*)d_in[9];
    const float* Wr2 = (const float*)d_in[10];
    const float* b2  = (const float*)d_in[11];
    const float* W3  = (const float*)d_in[12];
    const float* a3s = (const float*)d_in[13];
    const float* a3d = (const float*)d_in[14];
    const float* Wr3 = (const float*)d_in[15];
    const float* b3  = (const float*)d_in[16];
    float* out = (float*)d_out;

    const int* e_src = ei;
    const int* e_dst = ei + NEDGES;

    char* ws = (char*)d_ws;
    size_t off = 0;
    auto carve = [&](size_t bytes) { void* p = ws + off; off += (bytes + 255) & ~255ull; return p; };
    unsigned short* Fb = (unsigned short*)carve((size_t)MPAD * 512 * 2);
    unsigned short* Rb = (unsigned short*)carve((size_t)MPAD * 256 * 2);
    unsigned short* Hb = (unsigned short*)carve((size_t)MPAD * 256 * 2);
    short* xb   = (short*)carve((size_t)MPAD * 64 * 2);
    short* wc1  = (short*)carve((size_t)512 * 64 * 2);
    short* wc2  = (short*)carve((size_t)512 * 256 * 2);
    short* wc3  = (short*)carve((size_t)640 * 256 * 2);
    float* a3sp = (float*)carve(512 * 4);
    float* a3dp = (float*)carve(512 * 4);
    float* als  = (float*)carve((size_t)NNODES * NHEAD * 4);   // adjacent to ald:
    float* ald  = (float*)carve((size_t)NNODES * NHEAD * 4);   // one memset covers both
    float* p4   = (float*)carve((size_t)NEDGES * 4 * 4);
    int* csr_src = (int*)carve((size_t)NEDGES * 4);
    int* csr_dst = (int*)carve((size_t)NEDGES * 4);
    int* offsets = (int*)carve(((size_t)NNODES + 4) * 4);
    int* counts  = (int*)carve((size_t)NNODES * 4);
    int* partials = (int*)carve(256 * 4);
    int* pexcl    = (int*)carve(256 * 4);

    const int EB = (NEDGES + 255) / 256;
    const size_t AL_BYTES = (size_t)NNODES * NHEAD * 4 * 2;    // als + ald
    dim3 blk(256);

    // conversions (3 launches)
    convert_x<<<(MPAD * 64 + 255) / 256, blk, 0, stream>>>(x, xb);
    convert_pack1<<<(163840 + 255) / 256, blk, 0, stream>>>(W1, Wr1, W2, Wr2, wc1, wc2);
    convert_pack2<<<(164864 + 255) / 256, blk, 0, stream>>>(W3, Wr3, a3s, a3d, wc3, a3sp, a3dp);

    // CSR by dst (parallel scan; scatter mutates offsets into end-positions)
    hipMemsetAsync(counts, 0, NNODES * 4, stream);
    hist_kernel<<<EB, blk, 0, stream>>>(e_dst, counts, NEDGES);
    scan_local<<<SCANB, blk, 0, stream>>>(counts, offsets, partials);
    scan_partials<<<1, blk, 0, stream>>>(partials, pexcl);
    scan_carry<<<SCANB, blk, 0, stream>>>(offsets, pexcl);
    scatter_kernel<<<EB, blk, 0, stream>>>(e_src, e_dst, offsets, csr_src, csr_dst, NEDGES);

    // ---- layer 1 (K=64)
    hipMemsetAsync(als, 0, AL_BYTES, stream);
    mfma_gemm_fused<0><<<dim3(4, 313), blk, 0, stream>>>(xb, wc1, b1, a1s, a1d,
                                                         Fb, Rb, nullptr, als, ald, 64);
    edge_p<<<EB, blk, 0, stream>>>(als, ald, csr_src, csr_dst, p4, NEDGES);
    attn64_kernel<<<NNODES / 4, blk, 0, stream>>>(Fb, als, ald, offsets, csr_src, p4, Rb, Hb);

    // ---- layer 2 (K=256)
    hipMemsetAsync(als, 0, AL_BYTES, stream);
    mfma_gemm_fused<0><<<dim3(4, 313), blk, 0, stream>>>((short*)Hb, wc2, b2, a2s, a2d,
                                                         Fb, Rb, nullptr, als, ald, 256);
    edge_p<<<EB, blk, 0, stream>>>(als, ald, csr_src, csr_dst, p4, NEDGES);
    attn64_kernel<<<NNODES / 4, blk, 0, stream>>>(Fb, als, ald, offsets, csr_src, p4, Rb, Hb);

    // ---- layer 3 (K=256, N=640)
    hipMemsetAsync(als, 0, AL_BYTES, stream);
    mfma_gemm_fused<1><<<dim3(5, 313), blk, 0, stream>>>((short*)Hb, wc3, b3, a3sp, a3dp,
                                                         Fb, nullptr, out, als, ald, 256);
    edge_p<<<EB, blk, 0, stream>>>(als, ald, csr_src, csr_dst, p4, NEDGES);
    attn121_kernel<<<NNODES / 4, blk, 0, stream>>>(Fb, als, ald, offsets, csr_src, p4, out);
}

// Round 8
// 505.347 us; speedup vs baseline: 1.1519x; 1.0183x over previous
//
#include <hip/hip_runtime.h>
#include <hip/hip_bf16.h>

// GAT 3-layer: N=40000, E=400000 (+self-loops), H=4, HID=64, NCLS=121, F_IN=50.
// Round 8: kill the al-epilogue atomics. Each (row,head) logit dot is reduced
// by exactly 1 wave (mode 0) / 2 waves (mode 1) -> plain stores into
// half-split planes al4 = [als0|ald0|als1|ald1]; one upfront memset zeroes the
// half-1 planes; edge_p/attn sum halves. Everything else as round 7.

#define NNODES 40000
#define MPAD   40064    // 313 * 128
#define NEDGES 400000
#define FIN    50
#define NHEAD  4
#define SCANB  157      // ceil(40000/256)
#define N4     160000   // NNODES * NHEAD

typedef __attribute__((ext_vector_type(8))) short short8;
typedef __attribute__((ext_vector_type(4))) float float4v;
typedef __attribute__((ext_vector_type(4))) unsigned short ushort4v;
typedef __attribute__((ext_vector_type(8))) unsigned short ushort8v;

__device__ inline unsigned short f2bf(float f) {   // round-to-nearest-even bf16
    union { float f; unsigned u; } v; v.f = f;
    unsigned r = v.u + 0x7fff + ((v.u >> 16) & 1);
    return (unsigned short)(r >> 16);
}
__device__ inline float bf2f(unsigned short u) {
    union { unsigned u; float f; } v; v.u = ((unsigned)u) << 16; return v.f;
}
__device__ inline float lrelu(float x) { return x >= 0.f ? x : 0.2f * x; }

// ---------------------------------------------------------------- CSR build
__global__ void hist_kernel(const int* __restrict__ dst, int* __restrict__ counts, int E) {
    int i = blockIdx.x * blockDim.x + threadIdx.x;
    if (i < E) atomicAdd(&counts[dst[i]], 1);
}

__global__ __launch_bounds__(256) void scan_local(const int* __restrict__ counts,
                                                  int* __restrict__ offsets,
                                                  int* __restrict__ partials) {
    __shared__ int sh[256];
    int b = blockIdx.x, t = threadIdx.x, i = b * 256 + t;
    int v = (i < NNODES) ? counts[i] : 0;
    sh[t] = v;
    __syncthreads();
    #pragma unroll
    for (int off = 1; off < 256; off <<= 1) {
        int u = (t >= off) ? sh[t - off] : 0;
        __syncthreads();
        sh[t] += u;
        __syncthreads();
    }
    if (i < NNODES) offsets[i] = sh[t] - v;     // local exclusive
    if (t == 255) partials[b] = sh[255];
}

__global__ __launch_bounds__(256) void scan_partials(int* __restrict__ partials,
                                                     int* __restrict__ pexcl) {
    __shared__ int sh[256];
    int t = threadIdx.x;
    int v = (t < SCANB) ? partials[t] : 0;
    sh[t] = v;
    __syncthreads();
    #pragma unroll
    for (int off = 1; off < 256; off <<= 1) {
        int u = (t >= off) ? sh[t - off] : 0;
        __syncthreads();
        sh[t] += u;
        __syncthreads();
    }
    pexcl[t] = sh[t] - v;
}

__global__ __launch_bounds__(256) void scan_carry(int* __restrict__ offsets,
                                                  const int* __restrict__ pexcl) {
    int b = blockIdx.x, i = b * 256 + threadIdx.x;
    if (i < NNODES) offsets[i] += pexcl[b];
}

// mutates offsets: after this, offsets[d] = end(d); beg(d) = offsets[d-1] (0 for d=0)
__global__ void scatter_kernel(const int* __restrict__ src, const int* __restrict__ dst,
                               int* __restrict__ offsets,
                               int* __restrict__ csr_src, int* __restrict__ csr_dst, int E) {
    int i = blockIdx.x * blockDim.x + threadIdx.x;
    if (i < E) {
        int d = dst[i];
        int pos = atomicAdd(&offsets[d], 1);
        csr_src[pos] = src[i];
        csr_dst[pos] = d;
    }
}

// per-edge softmax numerators (no max subtraction; logits bounded). Sums halves.
__global__ void edge_p(const float* __restrict__ al4,
                       const int* __restrict__ csr_src, const int* __restrict__ csr_dst,
                       float* __restrict__ p4, int E) {
    int j = blockIdx.x * blockDim.x + threadIdx.x;
    if (j >= E) return;
    int s = csr_src[j], d = csr_dst[j];
    float4v a0 = *(const float4v*)&al4[s * 4];
    float4v a1 = *(const float4v*)&al4[2 * N4 + s * 4];
    float4v b0 = *(const float4v*)&al4[N4 + d * 4];
    float4v b1 = *(const float4v*)&al4[3 * N4 + d * 4];
    float4v p;
    p.x = __expf(lrelu(a0.x + a1.x + b0.x + b1.x));
    p.y = __expf(lrelu(a0.y + a1.y + b0.y + b1.y));
    p.z = __expf(lrelu(a0.z + a1.z + b0.z + b1.z));
    p.w = __expf(lrelu(a0.w + a1.w + b0.w + b1.w));
    *(float4v*)&p4[(size_t)j * 4] = p;
}

// ---------------------------------------------------------------- converts
__global__ void convert_x(const float* __restrict__ x, short* __restrict__ xb) {
    int i = blockIdx.x * blockDim.x + threadIdx.x;   // over MPAD*64
    if (i >= MPAD * 64) return;
    int r = i >> 6, k = i & 63;
    float v = (r < NNODES && k < FIN) ? x[r * FIN + k] : 0.f;
    xb[i] = f2bf(v);
}

// fused: wc1 = [W1^T|Wr1^T] (Kpad 64), wc2 = [W2^T|Wr2^T] (Kpad 256)
__global__ void convert_pack1(const float* __restrict__ W1, const float* __restrict__ Wr1,
                              const float* __restrict__ W2, const float* __restrict__ Wr2,
                              short* __restrict__ wc1, short* __restrict__ wc2) {
    int i = blockIdx.x * blockDim.x + threadIdx.x;
    if (i < 32768) {
        const float* W = (i < 16384) ? W1 : Wr1;
        int j = i & 16383;
        int n = j >> 6, k = j & 63;
        wc1[i] = f2bf((k < FIN) ? W[k * 256 + n] : 0.f);
    } else if (i < 163840) {
        int j = (i - 32768) & 65535;
        const float* W = (i < 98304) ? W2 : Wr2;
        int n = j >> 8, k = j & 255;
        wc2[(i - 32768)] = f2bf(W[k * 256 + n]);
    }
}

// fused: wc3 rows 0-511 = W3^T head-padded, rows 512-639 = Wr3^T; a3 pads [4][128]
__global__ void convert_pack2(const float* __restrict__ W3, const float* __restrict__ Wr3,
                              const float* __restrict__ a3s, const float* __restrict__ a3d,
                              short* __restrict__ wc3,
                              float* __restrict__ a3sp, float* __restrict__ a3dp) {
    int i = blockIdx.x * blockDim.x + threadIdx.x;
    if (i < 131072) {
        int j = i >> 8, k = i & 255;
        int h = j >> 7, c = j & 127;
        wc3[i] = f2bf((c < 121) ? W3[k * 484 + h * 121 + c] : 0.f);
    } else if (i < 163840) {
        int j = i - 131072;
        int n = j >> 8, k = j & 255;
        wc3[131072 + j] = f2bf((n < 121) ? Wr3[k * 121 + n] : 0.f);
    } else if (i < 164864) {
        int j = i - 163840;
        int which = j >> 9; int jj = j & 511;
        int h = jj >> 7, c = jj & 127;
        float v = (c < 121) ? (which ? a3d[h * 121 + c] : a3s[h * 121 + c]) : 0.f;
        (which ? a3dp : a3sp)[jj] = v;
    }
}

// ---------------------------------------------------------------- fused MFMA GEMM
// MODE 0 (layers 1-2): N=512 = [feat 256 | residual 256], both bf16, ld 256.
//   al-dot: head = 1 wave span -> store half 0.
// MODE 1 (layer 3):    N=640 = [feat 512 | out 121(pad128)], feat bf16 ld 512, out fp32.
//   al-dot: head = 2 wave spans -> store half (colbase>>6)&1.
// al4 planes: [als0 | ald0 | als1 | ald1], each N4 floats; half-1 pre-zeroed.
template<int MODE>
__global__ __launch_bounds__(256) void mfma_gemm_fused(const short* __restrict__ A,
                                                       const short* __restrict__ Bt,
                                                       const float* __restrict__ bias,
                                                       const float* __restrict__ asv,
                                                       const float* __restrict__ adv,
                                                       unsigned short* __restrict__ Fb,
                                                       unsigned short* __restrict__ Rb,
                                                       float* __restrict__ out,
                                                       float* __restrict__ al4,
                                                       int Kp) {
    const int NW = MODE ? 512 : 256;
    __shared__ __align__(16) short As[4096];
    const int tid = threadIdx.x;
    const int l   = tid & 63;
    const int w   = tid >> 6;
    const int wm  = w >> 1, wn = w & 1;
    const int row0 = blockIdx.y * 128;
    const int col0 = blockIdx.x * 128;
    const int lrow = l & 15;
    const int lq   = l >> 4;
    const int sr = (tid >> 6) * 16 + (tid & 15);
    const int sk = ((tid >> 4) & 3) * 8;

    float4v acc[4][4] = {};

    for (int k0 = 0; k0 < Kp; k0 += 32) {
        short8 a0 = *(const short8*)&A[(size_t)(row0 + sr) * Kp + k0 + sk];
        short8 a1 = *(const short8*)&A[(size_t)(row0 + 64 + sr) * Kp + k0 + sk];
        short8 bfrag[4];
        #pragma unroll
        for (int ct = 0; ct < 4; ++ct) {
            int col = col0 + wn * 64 + ct * 16 + lrow;
            bfrag[ct] = *(const short8*)&Bt[(size_t)col * Kp + k0 + lq * 8];
        }
        __syncthreads();
        *(short8*)&As[tid * 8] = a0;
        *(short8*)&As[(tid + 256) * 8] = a1;
        __syncthreads();
        #pragma unroll
        for (int rt = 0; rt < 4; ++rt) {
            short8 afrag = *(const short8*)&As[(wm * 4 + rt) * 512 + l * 8];
            #pragma unroll
            for (int ct = 0; ct < 4; ++ct)
                acc[rt][ct] = __builtin_amdgcn_mfma_f32_16x16x32_bf16(afrag, bfrag[ct],
                                                                      acc[rt][ct], 0, 0, 0);
        }
    }

    const int colbase = col0 + wn * 64;           // this wave's 64-col span start
    const bool isW = colbase < NW;

    // ---- stores
    #pragma unroll
    for (int ct = 0; ct < 4; ++ct) {
        int col = colbase + ct * 16 + lrow;
        #pragma unroll
        for (int rt = 0; rt < 4; ++rt) {
            int rbase = row0 + wm * 64 + rt * 16 + lq * 4;
            #pragma unroll
            for (int i = 0; i < 4; ++i) {
                int r = rbase + i;
                if (r >= NNODES) continue;
                float v = acc[rt][ct][i];
                if (MODE == 0) {
                    if (col < 256) Fb[(size_t)r * 256 + col] = f2bf(v);
                    else           Rb[(size_t)r * 256 + col - 256] = f2bf(v + bias[col - 256]);
                } else {
                    if (col < 512) Fb[(size_t)r * 512 + col] = f2bf(v);
                    else { int c = col - 512; if (c < 121) out[(size_t)r * 121 + c] = v + bias[c]; }
                }
            }
        }
    }

    // ---- al_s / al_d reduction (W-part only; plain stores, no atomics)
    if (isW) {
        const int head = (colbase * NHEAD) / NW;
        const int half = MODE ? ((colbase >> 6) & 1) : 0;
        float* als_o = al4 + (half ? 2 * N4 : 0);
        float* ald_o = als_o + N4;
        float as_c[4], ad_c[4];
        #pragma unroll
        for (int ct = 0; ct < 4; ++ct) {
            int col = colbase + ct * 16 + lrow;
            as_c[ct] = asv[col];
            ad_c[ct] = adv[col];
        }
        #pragma unroll
        for (int rt = 0; rt < 4; ++rt) {
            #pragma unroll
            for (int i = 0; i < 4; ++i) {
                int r = row0 + wm * 64 + rt * 16 + lq * 4 + i;
                float fs = 0.f, fd = 0.f;
                #pragma unroll
                for (int ct = 0; ct < 4; ++ct) {
                    float v = acc[rt][ct][i];
                    fs += v * as_c[ct];
                    fd += v * ad_c[ct];
                }
                #pragma unroll
                for (int o2 = 8; o2; o2 >>= 1) {
                    fs += __shfl_xor(fs, o2, 16);
                    fd += __shfl_xor(fd, o2, 16);
                }
                if (lrow == 0 && r < NNODES) {
                    als_o[r * 4 + head] = fs;
                    ald_o[r * 4 + head] = fd;
                }
            }
        }
    }
}

// --------------------------------------------------- attn layers 1-2 (C=64, concat)
// wave per node (4 heads in 16-lane groups), lane = 4 channels (8B gathers).
__global__ __launch_bounds__(256) void attn64_kernel(const unsigned short* __restrict__ featb,
                                                     const float* __restrict__ al4,
                                                     const int* __restrict__ offs,
                                                     const int* __restrict__ csr,
                                                     const float* __restrict__ p4,
                                                     const unsigned short* __restrict__ Rb,
                                                     unsigned short* __restrict__ outb) {
    int n = blockIdx.x * 4 + (threadIdx.x >> 6);
    int l = threadIdx.x & 63;
    int h = l >> 4;
    int beg = n ? offs[n - 1] : 0;
    int end = offs[n];

    float lg = al4[n * 4 + h] + al4[2 * N4 + n * 4 + h]
             + al4[N4 + n * 4 + h] + al4[3 * N4 + n * 4 + h];
    float p0 = __expf(lrelu(lg));                                // self-loop
    float s = p0;
    float a0, a1, a2, a3;
    {
        ushort4v f = *(const ushort4v*)&featb[(size_t)n * 256 + 4 * l];
        a0 = p0 * bf2f(f.x); a1 = p0 * bf2f(f.y); a2 = p0 * bf2f(f.z); a3 = p0 * bf2f(f.w);
    }
    #pragma unroll 8
    for (int j = beg; j < end; ++j) {
        int sn = csr[j];
        float p = p4[(size_t)j * 4 + h];
        s += p;
        ushort4v f = *(const ushort4v*)&featb[(size_t)sn * 256 + 4 * l];
        a0 += p * bf2f(f.x); a1 += p * bf2f(f.y); a2 += p * bf2f(f.z); a3 += p * bf2f(f.w);
    }
    float inv = 1.f / s;
    ushort4v r = *(const ushort4v*)&Rb[(size_t)n * 256 + 4 * l];
    ushort4v o;
    o.x = f2bf(fmaxf(bf2f(r.x) + a0 * inv, 0.f));
    o.y = f2bf(fmaxf(bf2f(r.y) + a1 * inv, 0.f));
    o.z = f2bf(fmaxf(bf2f(r.z) + a2 * inv, 0.f));
    o.w = f2bf(fmaxf(bf2f(r.w) + a3 * inv, 0.f));
    *(ushort4v*)&outb[(size_t)n * 256 + 4 * l] = o;
}

// --------------------------------------------------- attn layer 3 (C=121 pad 128, mean)
__global__ __launch_bounds__(256) void attn121_kernel(const unsigned short* __restrict__ featb,
                                                      const float* __restrict__ al4,
                                                      const int* __restrict__ offs,
                                                      const int* __restrict__ csr,
                                                      const float* __restrict__ p4,
                                                      float* __restrict__ out) {
    int n = blockIdx.x * 4 + (threadIdx.x >> 6);
    int l = threadIdx.x & 63;
    int h = l >> 4;
    int beg = n ? offs[n - 1] : 0;
    int end = offs[n];

    float lg = al4[n * 4 + h] + al4[2 * N4 + n * 4 + h]
             + al4[N4 + n * 4 + h] + al4[3 * N4 + n * 4 + h];
    float p0 = __expf(lrelu(lg));
    float s = p0;
    float a[8];
    {
        ushort8v f = *(const ushort8v*)&featb[(size_t)n * 512 + 8 * l];
        #pragma unroll
        for (int i = 0; i < 8; ++i) a[i] = p0 * bf2f(f[i]);
    }
    #pragma unroll 4
    for (int j = beg; j < end; ++j) {
        int sn = csr[j];
        float p = p4[(size_t)j * 4 + h];
        s += p;
        ushort8v f = *(const ushort8v*)&featb[(size_t)sn * 512 + 8 * l];
        #pragma unroll
        for (int i = 0; i < 8; ++i) a[i] += p * bf2f(f[i]);
    }
    float inv = 0.25f / s;                 // mean over heads
    #pragma unroll
    for (int i = 0; i < 8; ++i) {
        a[i] *= inv;
        a[i] += __shfl_xor(a[i], 16, 64);  // sum the 4 head groups
        a[i] += __shfl_xor(a[i], 32, 64);
    }
    if (l < 16) {
        #pragma unroll
        for (int i = 0; i < 8; ++i) {
            int c = 8 * l + i;
            if (c < 121) out[(size_t)n * 121 + c] += a[i];
        }
    }
}

// ---------------------------------------------------------------- launch
extern "C" void kernel_launch(void* const* d_in, const int* in_sizes, int n_in,
                              void* d_out, int out_size, void* d_ws, size_t ws_size,
                              hipStream_t stream) {
    const float* x   = (const float*)d_in[0];
    const int* ei    = (const int*)d_in[1];
    const float* W1  = (const float*)d_in[2];
    const float* a1s = (const float*)d_in[3];
    const float* a1d = (const float*)d_in[4];
    const float* Wr1 = (const float*)d_in[5];
    const float* b1  = (const float*)d_in[6];
    const float* W2  = (const float*)d_in[7];
    const float* a2s = (const float*)d_in[8];
    const float* a2d = (const float*)d_in[9];
    const float* Wr2 = (const float*)d_in[10];
    const float* b2  = (const float*)d_in[11];
    const float* W3  = (const float*)d_in[12];
    const float* a3s = (const float*)d_in[13];
    const float* a3d = (const float*)d_in[14];
    const float* Wr3 = (const float*)d_in[15];
    const float* b3  = (const float*)d_in[16];
    float* out = (float*)d_out;

    const int* e_src = ei;
    const int* e_dst = ei + NEDGES;

    char* ws = (char*)d_ws;
    size_t off = 0;
    auto carve = [&](size_t bytes) { void* p = ws + off; off += (bytes + 255) & ~255ull; return p; };
    unsigned short* Fb = (unsigned short*)carve((size_t)MPAD * 512 * 2);
    unsigned short* Rb = (unsigned short*)carve((size_t)MPAD * 256 * 2);
    unsigned short* Hb = (unsigned short*)carve((size_t)MPAD * 256 * 2);
    short* xb   = (short*)carve((size_t)MPAD * 64 * 2);
    short* wc1  = (short*)carve((size_t)512 * 64 * 2);
    short* wc2  = (short*)carve((size_t)512 * 256 * 2);
    short* wc3  = (short*)carve((size_t)640 * 256 * 2);
    float* a3sp = (float*)carve(512 * 4);
    float* a3dp = (float*)carve(512 * 4);
    float* al4  = (float*)carve((size_t)4 * N4 * 4);   // [als0|ald0|als1|ald1]
    float* p4   = (float*)carve((size_t)NEDGES * 4 * 4);
    int* csr_src = (int*)carve((size_t)NEDGES * 4);
    int* csr_dst = (int*)carve((size_t)NEDGES * 4);
    int* offsets = (int*)carve(((size_t)NNODES + 4) * 4);
    int* counts  = (int*)carve((size_t)NNODES * 4);
    int* partials = (int*)carve(256 * 4);
    int* pexcl    = (int*)carve(256 * 4);

    const int EB = (NEDGES + 255) / 256;
    dim3 blk(256);

    // conversions (3 launches)
    convert_x<<<(MPAD * 64 + 255) / 256, blk, 0, stream>>>(x, xb);
    convert_pack1<<<(163840 + 255) / 256, blk, 0, stream>>>(W1, Wr1, W2, Wr2, wc1, wc2);
    convert_pack2<<<(164864 + 255) / 256, blk, 0, stream>>>(W3, Wr3, a3s, a3d, wc3, a3sp, a3dp);

    // zero half-1 al planes once (layers 1-2 write half 0 only; layer 3 writes both)
    hipMemsetAsync(al4 + 2 * N4, 0, (size_t)2 * N4 * 4, stream);

    // CSR by dst (parallel scan; scatter mutates offsets into end-positions)
    hipMemsetAsync(counts, 0, NNODES * 4, stream);
    hist_kernel<<<EB, blk, 0, stream>>>(e_dst, counts, NEDGES);
    scan_local<<<SCANB, blk, 0, stream>>>(counts, offsets, partials);
    scan_partials<<<1, blk, 0, stream>>>(partials, pexcl);
    scan_carry<<<SCANB, blk, 0, stream>>>(offsets, pexcl);
    scatter_kernel<<<EB, blk, 0, stream>>>(e_src, e_dst, offsets, csr_src, csr_dst, NEDGES);

    // ---- layer 1 (K=64)
    mfma_gemm_fused<0><<<dim3(4, 313), blk, 0, stream>>>(xb, wc1, b1, a1s, a1d,
                                                         Fb, Rb, nullptr, al4, 64);
    edge_p<<<EB, blk, 0, stream>>>(al4, csr_src, csr_dst, p4, NEDGES);
    attn64_kernel<<<NNODES / 4, blk, 0, stream>>>(Fb, al4, offsets, csr_src, p4, Rb, Hb);

    // ---- layer 2 (K=256)
    mfma_gemm_fused<0><<<dim3(4, 313), blk, 0, stream>>>((short*)Hb, wc2, b2, a2s, a2d,
                                                         Fb, Rb, nullptr, al4, 256);
    edge_p<<<EB, blk, 0, stream>>>(al4, csr_src, csr_dst, p4, NEDGES);
    attn64_kernel<<<NNODES / 4, blk, 0, stream>>>(Fb, al4, offsets, csr_src, p4, Rb, Hb);

    // ---- layer 3 (K=256, N=640)
    mfma_gemm_fused<1><<<dim3(5, 313), blk, 0, stream>>>((short*)Hb, wc3, b3, a3sp, a3dp,
                                                         Fb, nullptr, out, al4, 256);
    edge_p<<<EB, blk, 0, stream>>>(al4, csr_src, csr_dst, p4, NEDGES);
    attn121_kernel<<<NNODES / 4, blk, 0, stream>>>(Fb, al4, offsets, csr_src, p4, out);
}

// Round 9
// 469.086 us; speedup vs baseline: 1.2410x; 1.0773x over previous
//
#include <hip/hip_runtime.h>
#include <hip/hip_bf16.h>

// GAT 3-layer: N=40000, E=400000 (+self-loops), H=4, HID=64, NCLS=121, F_IN=50.
// Round 9: GEMM epilogue was store-bound (64 scalar 2B stores/thread, 2x write
// amplification). Now: bf16 C-tile staged through LDS (Cs[2][32][132], two
// row-half passes, conflict-free write banks, ushort8 coalesced readback ->
// 8 vector 16B stores/thread). Bias folded pre-LDS. Mode-1 fp32 out block
// keeps scalar path. al epilogue (plain stores, half-split planes) unchanged.

#define NNODES 40000
#define MPAD   40064    // 313 * 128
#define NEDGES 400000
#define FIN    50
#define NHEAD  4
#define SCANB  157      // ceil(40000/256)
#define N4     160000   // NNODES * NHEAD

typedef __attribute__((ext_vector_type(8))) short short8;
typedef __attribute__((ext_vector_type(4))) float float4v;
typedef __attribute__((ext_vector_type(4))) unsigned short ushort4v;
typedef __attribute__((ext_vector_type(8))) unsigned short ushort8v;

__device__ inline unsigned short f2bf(float f) {   // round-to-nearest-even bf16
    union { float f; unsigned u; } v; v.f = f;
    unsigned r = v.u + 0x7fff + ((v.u >> 16) & 1);
    return (unsigned short)(r >> 16);
}
__device__ inline float bf2f(unsigned short u) {
    union { unsigned u; float f; } v; v.u = ((unsigned)u) << 16; return v.f;
}
__device__ inline float lrelu(float x) { return x >= 0.f ? x : 0.2f * x; }

// ---------------------------------------------------------------- CSR build
__global__ void hist_kernel(const int* __restrict__ dst, int* __restrict__ counts, int E) {
    int i = blockIdx.x * blockDim.x + threadIdx.x;
    if (i < E) atomicAdd(&counts[dst[i]], 1);
}

__global__ __launch_bounds__(256) void scan_local(const int* __restrict__ counts,
                                                  int* __restrict__ offsets,
                                                  int* __restrict__ partials) {
    __shared__ int sh[256];
    int b = blockIdx.x, t = threadIdx.x, i = b * 256 + t;
    int v = (i < NNODES) ? counts[i] : 0;
    sh[t] = v;
    __syncthreads();
    #pragma unroll
    for (int off = 1; off < 256; off <<= 1) {
        int u = (t >= off) ? sh[t - off] : 0;
        __syncthreads();
        sh[t] += u;
        __syncthreads();
    }
    if (i < NNODES) offsets[i] = sh[t] - v;     // local exclusive
    if (t == 255) partials[b] = sh[255];
}

__global__ __launch_bounds__(256) void scan_partials(int* __restrict__ partials,
                                                     int* __restrict__ pexcl) {
    __shared__ int sh[256];
    int t = threadIdx.x;
    int v = (t < SCANB) ? partials[t] : 0;
    sh[t] = v;
    __syncthreads();
    #pragma unroll
    for (int off = 1; off < 256; off <<= 1) {
        int u = (t >= off) ? sh[t - off] : 0;
        __syncthreads();
        sh[t] += u;
        __syncthreads();
    }
    pexcl[t] = sh[t] - v;
}

__global__ __launch_bounds__(256) void scan_carry(int* __restrict__ offsets,
                                                  const int* __restrict__ pexcl) {
    int b = blockIdx.x, i = b * 256 + threadIdx.x;
    if (i < NNODES) offsets[i] += pexcl[b];
}

// mutates offsets: after this, offsets[d] = end(d); beg(d) = offsets[d-1] (0 for d=0)
__global__ void scatter_kernel(const int* __restrict__ src, const int* __restrict__ dst,
                               int* __restrict__ offsets,
                               int* __restrict__ csr_src, int* __restrict__ csr_dst, int E) {
    int i = blockIdx.x * blockDim.x + threadIdx.x;
    if (i < E) {
        int d = dst[i];
        int pos = atomicAdd(&offsets[d], 1);
        csr_src[pos] = src[i];
        csr_dst[pos] = d;
    }
}

// per-edge softmax numerators (no max subtraction; logits bounded). Sums halves.
__global__ void edge_p(const float* __restrict__ al4,
                       const int* __restrict__ csr_src, const int* __restrict__ csr_dst,
                       float* __restrict__ p4, int E) {
    int j = blockIdx.x * blockDim.x + threadIdx.x;
    if (j >= E) return;
    int s = csr_src[j], d = csr_dst[j];
    float4v a0 = *(const float4v*)&al4[s * 4];
    float4v a1 = *(const float4v*)&al4[2 * N4 + s * 4];
    float4v b0 = *(const float4v*)&al4[N4 + d * 4];
    float4v b1 = *(const float4v*)&al4[3 * N4 + d * 4];
    float4v p;
    p.x = __expf(lrelu(a0.x + a1.x + b0.x + b1.x));
    p.y = __expf(lrelu(a0.y + a1.y + b0.y + b1.y));
    p.z = __expf(lrelu(a0.z + a1.z + b0.z + b1.z));
    p.w = __expf(lrelu(a0.w + a1.w + b0.w + b1.w));
    *(float4v*)&p4[(size_t)j * 4] = p;
}

// ---------------------------------------------------------------- converts
__global__ void convert_x(const float* __restrict__ x, short* __restrict__ xb) {
    int i = blockIdx.x * blockDim.x + threadIdx.x;   // over MPAD*64
    if (i >= MPAD * 64) return;
    int r = i >> 6, k = i & 63;
    float v = (r < NNODES && k < FIN) ? x[r * FIN + k] : 0.f;
    xb[i] = f2bf(v);
}

// fused: wc1 = [W1^T|Wr1^T] (Kpad 64), wc2 = [W2^T|Wr2^T] (Kpad 256)
__global__ void convert_pack1(const float* __restrict__ W1, const float* __restrict__ Wr1,
                              const float* __restrict__ W2, const float* __restrict__ Wr2,
                              short* __restrict__ wc1, short* __restrict__ wc2) {
    int i = blockIdx.x * blockDim.x + threadIdx.x;
    if (i < 32768) {
        const float* W = (i < 16384) ? W1 : Wr1;
        int j = i & 16383;
        int n = j >> 6, k = j & 63;
        wc1[i] = f2bf((k < FIN) ? W[k * 256 + n] : 0.f);
    } else if (i < 163840) {
        int j = (i - 32768) & 65535;
        const float* W = (i < 98304) ? W2 : Wr2;
        int n = j >> 8, k = j & 255;
        wc2[(i - 32768)] = f2bf(W[k * 256 + n]);
    }
}

// fused: wc3 rows 0-511 = W3^T head-padded, rows 512-639 = Wr3^T; a3 pads [4][128]
__global__ void convert_pack2(const float* __restrict__ W3, const float* __restrict__ Wr3,
                              const float* __restrict__ a3s, const float* __restrict__ a3d,
                              short* __restrict__ wc3,
                              float* __restrict__ a3sp, float* __restrict__ a3dp) {
    int i = blockIdx.x * blockDim.x + threadIdx.x;
    if (i < 131072) {
        int j = i >> 8, k = i & 255;
        int h = j >> 7, c = j & 127;
        wc3[i] = f2bf((c < 121) ? W3[k * 484 + h * 121 + c] : 0.f);
    } else if (i < 163840) {
        int j = i - 131072;
        int n = j >> 8, k = j & 255;
        wc3[131072 + j] = f2bf((n < 121) ? Wr3[k * 121 + n] : 0.f);
    } else if (i < 164864) {
        int j = i - 163840;
        int which = j >> 9; int jj = j & 511;
        int h = jj >> 7, c = jj & 127;
        float v = (c < 121) ? (which ? a3d[h * 121 + c] : a3s[h * 121 + c]) : 0.f;
        (which ? a3dp : a3sp)[jj] = v;
    }
}

// ---------------------------------------------------------------- fused MFMA GEMM
// MODE 0 (layers 1-2): N=512 = [feat 256 | residual 256], both bf16, ld 256.
// MODE 1 (layer 3):    N=640 = [feat 512 | out 121(pad128) fp32 scalar path].
// bf16 blocks: C-tile -> LDS (2 row-half passes) -> ushort8 coalesced stores.
// al4 planes: [als0 | ald0 | als1 | ald1], each N4 floats; half-1 pre-zeroed.
template<int MODE>
__global__ __launch_bounds__(256) void mfma_gemm_fused(const short* __restrict__ A,
                                                       const short* __restrict__ Bt,
                                                       const float* __restrict__ bias,
                                                       const float* __restrict__ asv,
                                                       const float* __restrict__ adv,
                                                       unsigned short* __restrict__ Fb,
                                                       unsigned short* __restrict__ Rb,
                                                       float* __restrict__ out,
                                                       float* __restrict__ al4,
                                                       int Kp) {
    const int NW = MODE ? 512 : 256;
    __shared__ __align__(16) short As[4096];
    __shared__ __align__(16) unsigned short Cs[2][32][132];
    const int tid = threadIdx.x;
    const int l   = tid & 63;
    const int w   = tid >> 6;
    const int wm  = w >> 1, wn = w & 1;
    const int row0 = blockIdx.y * 128;
    const int col0 = blockIdx.x * 128;
    const int lrow = l & 15;
    const int lq   = l >> 4;
    const int sr = (tid >> 6) * 16 + (tid & 15);
    const int sk = ((tid >> 4) & 3) * 8;

    float4v acc[4][4] = {};

    for (int k0 = 0; k0 < Kp; k0 += 32) {
        short8 a0 = *(const short8*)&A[(size_t)(row0 + sr) * Kp + k0 + sk];
        short8 a1 = *(const short8*)&A[(size_t)(row0 + 64 + sr) * Kp + k0 + sk];
        short8 bfrag[4];
        #pragma unroll
        for (int ct = 0; ct < 4; ++ct) {
            int col = col0 + wn * 64 + ct * 16 + lrow;
            bfrag[ct] = *(const short8*)&Bt[(size_t)col * Kp + k0 + lq * 8];
        }
        __syncthreads();
        *(short8*)&As[tid * 8] = a0;
        *(short8*)&As[(tid + 256) * 8] = a1;
        __syncthreads();
        #pragma unroll
        for (int rt = 0; rt < 4; ++rt) {
            short8 afrag = *(const short8*)&As[(wm * 4 + rt) * 512 + l * 8];
            #pragma unroll
            for (int ct = 0; ct < 4; ++ct)
                acc[rt][ct] = __builtin_amdgcn_mfma_f32_16x16x32_bf16(afrag, bfrag[ct],
                                                                      acc[rt][ct], 0, 0, 0);
        }
    }

    const int colbase = col0 + wn * 64;           // this wave's 64-col span start
    const bool isW = colbase < NW;

    // ---- al_s / al_d reduction (W-part only; plain stores, no atomics)
    if (isW) {
        const int head = (colbase * NHEAD) / NW;
        const int half = MODE ? ((colbase >> 6) & 1) : 0;
        float* als_o = al4 + (half ? 2 * N4 : 0);
        float* ald_o = als_o + N4;
        float as_c[4], ad_c[4];
        #pragma unroll
        for (int ct = 0; ct < 4; ++ct) {
            int col = colbase + ct * 16 + lrow;
            as_c[ct] = asv[col];
            ad_c[ct] = adv[col];
        }
        #pragma unroll
        for (int rt = 0; rt < 4; ++rt) {
            #pragma unroll
            for (int i = 0; i < 4; ++i) {
                int r = row0 + wm * 64 + rt * 16 + lq * 4 + i;
                float fs = 0.f, fd = 0.f;
                #pragma unroll
                for (int ct = 0; ct < 4; ++ct) {
                    float v = acc[rt][ct][i];
                    fs += v * as_c[ct];
                    fd += v * ad_c[ct];
                }
                #pragma unroll
                for (int o2 = 8; o2; o2 >>= 1) {
                    fs += __shfl_xor(fs, o2, 16);
                    fd += __shfl_xor(fd, o2, 16);
                }
                if (lrow == 0 && r < NNODES) {
                    als_o[r * 4 + head] = fs;
                    ald_o[r * 4 + head] = fd;
                }
            }
        }
    }

    // ---- stores
    if (MODE == 1 && col0 >= 512) {
        // fp32 out block (121 real cols): scalar path
        #pragma unroll
        for (int ct = 0; ct < 4; ++ct) {
            int c = colbase + ct * 16 + lrow - 512;
            if (c >= 121) continue;
            float bv = bias[c];
            #pragma unroll
            for (int rt = 0; rt < 4; ++rt) {
                int rbase = row0 + wm * 64 + rt * 16 + lq * 4;
                #pragma unroll
                for (int i = 0; i < 4; ++i) {
                    int r = rbase + i;
                    if (r < NNODES) out[(size_t)r * 121 + c] = acc[rt][ct][i] + bv;
                }
            }
        }
        return;
    }

    // bf16 destination for this block (block-uniform)
    const bool isRb = (MODE == 0) && (col0 >= 256);
    unsigned short* dest = isRb ? Rb : Fb;
    const int ldd = MODE ? 512 : 256;
    const int cold = isRb ? col0 - 256 : col0;
    float badd[4] = {0.f, 0.f, 0.f, 0.f};
    if (isRb) {
        #pragma unroll
        for (int ct = 0; ct < 4; ++ct)
            badd[ct] = bias[col0 - 256 + wn * 64 + ct * 16 + lrow];
    }

    const int rp = tid >> 2, g = rp >> 5, rr = rp & 31, q = tid & 3;
    #pragma unroll
    for (int p = 0; p < 2; ++p) {
        if (p) __syncthreads();
        #pragma unroll
        for (int rt2 = 0; rt2 < 2; ++rt2) {
            int rt = p * 2 + rt2;
            #pragma unroll
            for (int ct = 0; ct < 4; ++ct) {
                int cl = wn * 64 + ct * 16 + lrow;
                #pragma unroll
                for (int i = 0; i < 4; ++i) {
                    int lr = rt2 * 16 + lq * 4 + i;
                    Cs[wm][lr][cl] = f2bf(acc[rt][ct][i] + badd[ct]);
                }
            }
        }
        __syncthreads();
        int grow = row0 + g * 64 + p * 32 + rr;
        if (grow < NNODES) {
            #pragma unroll
            for (int k = 0; k < 4; ++k) {
                ushort8v v = *(const ushort8v*)&Cs[g][rr][q * 32 + 8 * k];
                *(ushort8v*)&dest[(size_t)grow * ldd + cold + q * 32 + 8 * k] = v;
            }
        }
    }
}

// --------------------------------------------------- attn layers 1-2 (C=64, concat)
// wave per node (4 heads in 16-lane groups), lane = 4 channels (8B gathers).
__global__ __launch_bounds__(256) void attn64_kernel(const unsigned short* __restrict__ featb,
                                                     const float* __restrict__ al4,
                                                     const int* __restrict__ offs,
                                                     const int* __restrict__ csr,
                                                     const float* __restrict__ p4,
                                                     const unsigned short* __restrict__ Rb,
                                                     unsigned short* __restrict__ outb) {
    int n = blockIdx.x * 4 + (threadIdx.x >> 6);
    int l = threadIdx.x & 63;
    int h = l >> 4;
    int beg = n ? offs[n - 1] : 0;
    int end = offs[n];

    float lg = al4[n * 4 + h] + al4[2 * N4 + n * 4 + h]
             + al4[N4 + n * 4 + h] + al4[3 * N4 + n * 4 + h];
    float p0 = __expf(lrelu(lg));                                // self-loop
    float s = p0;
    float a0, a1, a2, a3;
    {
        ushort4v f = *(const ushort4v*)&featb[(size_t)n * 256 + 4 * l];
        a0 = p0 * bf2f(f.x); a1 = p0 * bf2f(f.y); a2 = p0 * bf2f(f.z); a3 = p0 * bf2f(f.w);
    }
    #pragma unroll 8
    for (int j = beg; j < end; ++j) {
        int sn = csr[j];
        float p = p4[(size_t)j * 4 + h];
        s += p;
        ushort4v f = *(const ushort4v*)&featb[(size_t)sn * 256 + 4 * l];
        a0 += p * bf2f(f.x); a1 += p * bf2f(f.y); a2 += p * bf2f(f.z); a3 += p * bf2f(f.w);
    }
    float inv = 1.f / s;
    ushort4v r = *(const ushort4v*)&Rb[(size_t)n * 256 + 4 * l];
    ushort4v o;
    o.x = f2bf(fmaxf(bf2f(r.x) + a0 * inv, 0.f));
    o.y = f2bf(fmaxf(bf2f(r.y) + a1 * inv, 0.f));
    o.z = f2bf(fmaxf(bf2f(r.z) + a2 * inv, 0.f));
    o.w = f2bf(fmaxf(bf2f(r.w) + a3 * inv, 0.f));
    *(ushort4v*)&outb[(size_t)n * 256 + 4 * l] = o;
}

// --------------------------------------------------- attn layer 3 (C=121 pad 128, mean)
__global__ __launch_bounds__(256) void attn121_kernel(const unsigned short* __restrict__ featb,
                                                      const float* __restrict__ al4,
                                                      const int* __restrict__ offs,
                                                      const int* __restrict__ csr,
                                                      const float* __restrict__ p4,
                                                      float* __restrict__ out) {
    int n = blockIdx.x * 4 + (threadIdx.x >> 6);
    int l = threadIdx.x & 63;
    int h = l >> 4;
    int beg = n ? offs[n - 1] : 0;
    int end = offs[n];

    float lg = al4[n * 4 + h] + al4[2 * N4 + n * 4 + h]
             + al4[N4 + n * 4 + h] + al4[3 * N4 + n * 4 + h];
    float p0 = __expf(lrelu(lg));
    float s = p0;
    float a[8];
    {
        ushort8v f = *(const ushort8v*)&featb[(size_t)n * 512 + 8 * l];
        #pragma unroll
        for (int i = 0; i < 8; ++i) a[i] = p0 * bf2f(f[i]);
    }
    #pragma unroll 4
    for (int j = beg; j < end; ++j) {
        int sn = csr[j];
        float p = p4[(size_t)j * 4 + h];
        s += p;
        ushort8v f = *(const ushort8v*)&featb[(size_t)sn * 512 + 8 * l];
        #pragma unroll
        for (int i = 0; i < 8; ++i) a[i] += p * bf2f(f[i]);
    }
    float inv = 0.25f / s;                 // mean over heads
    #pragma unroll
    for (int i = 0; i < 8; ++i) {
        a[i] *= inv;
        a[i] += __shfl_xor(a[i], 16, 64);  // sum the 4 head groups
        a[i] += __shfl_xor(a[i], 32, 64);
    }
    if (l < 16) {
        #pragma unroll
        for (int i = 0; i < 8; ++i) {
            int c = 8 * l + i;
            if (c < 121) out[(size_t)n * 121 + c] += a[i];
        }
    }
}

// ---------------------------------------------------------------- launch
extern "C" void kernel_launch(void* const* d_in, const int* in_sizes, int n_in,
                              void* d_out, int out_size, void* d_ws, size_t ws_size,
                              hipStream_t stream) {
    const float* x   = (const float*)d_in[0];
    const int* ei    = (const int*)d_in[1];
    const float* W1  = (const float*)d_in[2];
    const float* a1s = (const float*)d_in[3];
    const float* a1d = (const float*)d_in[4];
    const float* Wr1 = (const float*)d_in[5];
    const float* b1  = (const float*)d_in[6];
    const float* W2  = (const float*)d_in[7];
    const float* a2s = (const float*)d_in[8];
    const float* a2d = (const float*)d_in[9];
    const float* Wr2 = (const float*)d_in[10];
    const float* b2  = (const float*)d_in[11];
    const float* W3  = (const float*)d_in[12];
    const float* a3s = (const float*)d_in[13];
    const float* a3d = (const float*)d_in[14];
    const float* Wr3 = (const float*)d_in[15];
    const float* b3  = (const float*)d_in[16];
    float* out = (float*)d_out;

    const int* e_src = ei;
    const int* e_dst = ei + NEDGES;

    char* ws = (char*)d_ws;
    size_t off = 0;
    auto carve = [&](size_t bytes) { void* p = ws + off; off += (bytes + 255) & ~255ull; return p; };
    unsigned short* Fb = (unsigned short*)carve((size_t)MPAD * 512 * 2);
    unsigned short* Rb = (unsigned short*)carve((size_t)MPAD * 256 * 2);
    unsigned short* Hb = (unsigned short*)carve((size_t)MPAD * 256 * 2);
    short* xb   = (short*)carve((size_t)MPAD * 64 * 2);
    short* wc1  = (short*)carve((size_t)512 * 64 * 2);
    short* wc2  = (short*)carve((size_t)512 * 256 * 2);
    short* wc3  = (short*)carve((size_t)640 * 256 * 2);
    float* a3sp = (float*)carve(512 * 4);
    float* a3dp = (float*)carve(512 * 4);
    float* al4  = (float*)carve((size_t)4 * N4 * 4);   // [als0|ald0|als1|ald1]
    float* p4   = (float*)carve((size_t)NEDGES * 4 * 4);
    int* csr_src = (int*)carve((size_t)NEDGES * 4);
    int* csr_dst = (int*)carve((size_t)NEDGES * 4);
    int* offsets = (int*)carve(((size_t)NNODES + 4) * 4);
    int* counts  = (int*)carve((size_t)NNODES * 4);
    int* partials = (int*)carve(256 * 4);
    int* pexcl    = (int*)carve(256 * 4);

    const int EB = (NEDGES + 255) / 256;
    dim3 blk(256);

    // conversions (3 launches)
    convert_x<<<(MPAD * 64 + 255) / 256, blk, 0, stream>>>(x, xb);
    convert_pack1<<<(163840 + 255) / 256, blk, 0, stream>>>(W1, Wr1, W2, Wr2, wc1, wc2);
    convert_pack2<<<(164864 + 255) / 256, blk, 0, stream>>>(W3, Wr3, a3s, a3d, wc3, a3sp, a3dp);

    // zero half-1 al planes once (layers 1-2 write half 0 only; layer 3 writes both)
    hipMemsetAsync(al4 + 2 * N4, 0, (size_t)2 * N4 * 4, stream);

    // CSR by dst (parallel scan; scatter mutates offsets into end-positions)
    hipMemsetAsync(counts, 0, NNODES * 4, stream);
    hist_kernel<<<EB, blk, 0, stream>>>(e_dst, counts, NEDGES);
    scan_local<<<SCANB, blk, 0, stream>>>(counts, offsets, partials);
    scan_partials<<<1, blk, 0, stream>>>(partials, pexcl);
    scan_carry<<<SCANB, blk, 0, stream>>>(offsets, pexcl);
    scatter_kernel<<<EB, blk, 0, stream>>>(e_src, e_dst, offsets, csr_src, csr_dst, NEDGES);

    // ---- layer 1 (K=64)
    mfma_gemm_fused<0><<<dim3(4, 313), blk, 0, stream>>>(xb, wc1, b1, a1s, a1d,
                                                         Fb, Rb, nullptr, al4, 64);
    edge_p<<<EB, blk, 0, stream>>>(al4, csr_src, csr_dst, p4, NEDGES);
    attn64_kernel<<<NNODES / 4, blk, 0, stream>>>(Fb, al4, offsets, csr_src, p4, Rb, Hb);

    // ---- layer 2 (K=256)
    mfma_gemm_fused<0><<<dim3(4, 313), blk, 0, stream>>>((short*)Hb, wc2, b2, a2s, a2d,
                                                         Fb, Rb, nullptr, al4, 256);
    edge_p<<<EB, blk, 0, stream>>>(al4, csr_src, csr_dst, p4, NEDGES);
    attn64_kernel<<<NNODES / 4, blk, 0, stream>>>(Fb, al4, offsets, csr_src, p4, Rb, Hb);

    // ---- layer 3 (K=256, N=640)
    mfma_gemm_fused<1><<<dim3(5, 313), blk, 0, stream>>>((short*)Hb, wc3, b3, a3sp, a3dp,
                                                         Fb, nullptr, out, al4, 256);
    edge_p<<<EB, blk, 0, stream>>>(al4, csr_src, csr_dst, p4, NEDGES);
    attn121_kernel<<<NNODES / 4, blk, 0, stream>>>(Fb, al4, offsets, csr_src, p4, out);
}

// Round 10
// 452.463 us; speedup vs baseline: 1.2866x; 1.0367x over previous
//
#include <hip/hip_runtime.h>
#include <hip/hip_bf16.h>

// GAT 3-layer: N=40000, E=400000 (+self-loops), H=4, HID=64, NCLS=121, F_IN=50.
// Round 10: edge-phase gather optimization. (1) layer-3 feat re-encoded fp8
// e4m3 (hardware cvt_pk) -> 20.5 MB gather table (was 41), decode via
// v_cvt_pk_f32_fp8. (2) attn kernels process 2 edges/iteration (half-wave per
// edge, 16B/lane), halves combined with shfl_xor(32). GEMM/CSR as round 9.

#define NNODES 40000
#define MPAD   40064    // 313 * 128
#define NEDGES 400000
#define FIN    50
#define NHEAD  4
#define SCANB  157      // ceil(40000/256)
#define N4     160000   // NNODES * NHEAD

typedef __attribute__((ext_vector_type(8))) short short8;
typedef __attribute__((ext_vector_type(4))) float float4v;
typedef __attribute__((ext_vector_type(2))) float float2v;
typedef __attribute__((ext_vector_type(4))) unsigned short ushort4v;
typedef __attribute__((ext_vector_type(8))) unsigned short ushort8v;
typedef __attribute__((ext_vector_type(4))) unsigned int uint4v;

__device__ inline unsigned short f2bf(float f) {   // round-to-nearest-even bf16
    union { float f; unsigned u; } v; v.f = f;
    unsigned r = v.u + 0x7fff + ((v.u >> 16) & 1);
    return (unsigned short)(r >> 16);
}
__device__ inline float bf2f(unsigned short u) {
    union { unsigned u; float f; } v; v.u = ((unsigned)u) << 16; return v.f;
}
__device__ inline float lrelu(float x) { return x >= 0.f ? x : 0.2f * x; }

// ---------------------------------------------------------------- CSR build
__global__ void hist_kernel(const int* __restrict__ dst, int* __restrict__ counts, int E) {
    int i = blockIdx.x * blockDim.x + threadIdx.x;
    if (i < E) atomicAdd(&counts[dst[i]], 1);
}

__global__ __launch_bounds__(256) void scan_local(const int* __restrict__ counts,
                                                  int* __restrict__ offsets,
                                                  int* __restrict__ partials) {
    __shared__ int sh[256];
    int b = blockIdx.x, t = threadIdx.x, i = b * 256 + t;
    int v = (i < NNODES) ? counts[i] : 0;
    sh[t] = v;
    __syncthreads();
    #pragma unroll
    for (int off = 1; off < 256; off <<= 1) {
        int u = (t >= off) ? sh[t - off] : 0;
        __syncthreads();
        sh[t] += u;
        __syncthreads();
    }
    if (i < NNODES) offsets[i] = sh[t] - v;     // local exclusive
    if (t == 255) partials[b] = sh[255];
}

__global__ __launch_bounds__(256) void scan_partials(int* __restrict__ partials,
                                                     int* __restrict__ pexcl) {
    __shared__ int sh[256];
    int t = threadIdx.x;
    int v = (t < SCANB) ? partials[t] : 0;
    sh[t] = v;
    __syncthreads();
    #pragma unroll
    for (int off = 1; off < 256; off <<= 1) {
        int u = (t >= off) ? sh[t - off] : 0;
        __syncthreads();
        sh[t] += u;
        __syncthreads();
    }
    pexcl[t] = sh[t] - v;
}

__global__ __launch_bounds__(256) void scan_carry(int* __restrict__ offsets,
                                                  const int* __restrict__ pexcl) {
    int b = blockIdx.x, i = b * 256 + threadIdx.x;
    if (i < NNODES) offsets[i] += pexcl[b];
}

// mutates offsets: after this, offsets[d] = end(d); beg(d) = offsets[d-1] (0 for d=0)
__global__ void scatter_kernel(const int* __restrict__ src, const int* __restrict__ dst,
                               int* __restrict__ offsets,
                               int* __restrict__ csr_src, int* __restrict__ csr_dst, int E) {
    int i = blockIdx.x * blockDim.x + threadIdx.x;
    if (i < E) {
        int d = dst[i];
        int pos = atomicAdd(&offsets[d], 1);
        csr_src[pos] = src[i];
        csr_dst[pos] = d;
    }
}

// per-edge softmax numerators (no max subtraction; logits bounded). Sums halves.
__global__ void edge_p(const float* __restrict__ al4,
                       const int* __restrict__ csr_src, const int* __restrict__ csr_dst,
                       float* __restrict__ p4, int E) {
    int j = blockIdx.x * blockDim.x + threadIdx.x;
    if (j >= E) return;
    int s = csr_src[j], d = csr_dst[j];
    float4v a0 = *(const float4v*)&al4[s * 4];
    float4v a1 = *(const float4v*)&al4[2 * N4 + s * 4];
    float4v b0 = *(const float4v*)&al4[N4 + d * 4];
    float4v b1 = *(const float4v*)&al4[3 * N4 + d * 4];
    float4v p;
    p.x = __expf(lrelu(a0.x + a1.x + b0.x + b1.x));
    p.y = __expf(lrelu(a0.y + a1.y + b0.y + b1.y));
    p.z = __expf(lrelu(a0.z + a1.z + b0.z + b1.z));
    p.w = __expf(lrelu(a0.w + a1.w + b0.w + b1.w));
    *(float4v*)&p4[(size_t)j * 4] = p;
}

// ---------------------------------------------------------------- converts
__global__ void convert_x(const float* __restrict__ x, short* __restrict__ xb) {
    int i = blockIdx.x * blockDim.x + threadIdx.x;   // over MPAD*64
    if (i >= MPAD * 64) return;
    int r = i >> 6, k = i & 63;
    float v = (r < NNODES && k < FIN) ? x[r * FIN + k] : 0.f;
    xb[i] = f2bf(v);
}

// fused: wc1 = [W1^T|Wr1^T] (Kpad 64), wc2 = [W2^T|Wr2^T] (Kpad 256)
__global__ void convert_pack1(const float* __restrict__ W1, const float* __restrict__ Wr1,
                              const float* __restrict__ W2, const float* __restrict__ Wr2,
                              short* __restrict__ wc1, short* __restrict__ wc2) {
    int i = blockIdx.x * blockDim.x + threadIdx.x;
    if (i < 32768) {
        const float* W = (i < 16384) ? W1 : Wr1;
        int j = i & 16383;
        int n = j >> 6, k = j & 63;
        wc1[i] = f2bf((k < FIN) ? W[k * 256 + n] : 0.f);
    } else if (i < 163840) {
        int j = (i - 32768) & 65535;
        const float* W = (i < 98304) ? W2 : Wr2;
        int n = j >> 8, k = j & 255;
        wc2[(i - 32768)] = f2bf(W[k * 256 + n]);
    }
}

// fused: wc3 rows 0-511 = W3^T head-padded, rows 512-639 = Wr3^T; a3 pads [4][128]
__global__ void convert_pack2(const float* __restrict__ W3, const float* __restrict__ Wr3,
                              const float* __restrict__ a3s, const float* __restrict__ a3d,
                              short* __restrict__ wc3,
                              float* __restrict__ a3sp, float* __restrict__ a3dp) {
    int i = blockIdx.x * blockDim.x + threadIdx.x;
    if (i < 131072) {
        int j = i >> 8, k = i & 255;
        int h = j >> 7, c = j & 127;
        wc3[i] = f2bf((c < 121) ? W3[k * 484 + h * 121 + c] : 0.f);
    } else if (i < 163840) {
        int j = i - 131072;
        int n = j >> 8, k = j & 255;
        wc3[131072 + j] = f2bf((n < 121) ? Wr3[k * 121 + n] : 0.f);
    } else if (i < 164864) {
        int j = i - 163840;
        int which = j >> 9; int jj = j & 511;
        int h = jj >> 7, c = jj & 127;
        float v = (c < 121) ? (which ? a3d[h * 121 + c] : a3s[h * 121 + c]) : 0.f;
        (which ? a3dp : a3sp)[jj] = v;
    }
}

// bf16 feat [NNODES][512] -> fp8 e4m3 packed uints [NNODES][128]
__global__ void convert_f8(const unsigned short* __restrict__ Fb, unsigned int* __restrict__ F8) {
    int i = blockIdx.x * blockDim.x + threadIdx.x;   // one uint (4 fp8) per thread
    if (i >= NNODES * 128) return;
    ushort4v f = *(const ushort4v*)&Fb[(size_t)i * 4];
    int v = 0;
    v = __builtin_amdgcn_cvt_pk_fp8_f32(bf2f(f.x), bf2f(f.y), v, false);
    v = __builtin_amdgcn_cvt_pk_fp8_f32(bf2f(f.z), bf2f(f.w), v, true);
    F8[i] = (unsigned int)v;
}

// ---------------------------------------------------------------- fused MFMA GEMM
// MODE 0 (layers 1-2): N=512 = [feat 256 | residual 256], both bf16, ld 256.
// MODE 1 (layer 3):    N=640 = [feat 512 | out 121(pad128) fp32 scalar path].
// bf16 blocks: C-tile -> LDS (2 row-half passes) -> ushort8 coalesced stores.
// al4 planes: [als0 | ald0 | als1 | ald1], each N4 floats; half-1 pre-zeroed.
template<int MODE>
__global__ __launch_bounds__(256) void mfma_gemm_fused(const short* __restrict__ A,
                                                       const short* __restrict__ Bt,
                                                       const float* __restrict__ bias,
                                                       const float* __restrict__ asv,
                                                       const float* __restrict__ adv,
                                                       unsigned short* __restrict__ Fb,
                                                       unsigned short* __restrict__ Rb,
                                                       float* __restrict__ out,
                                                       float* __restrict__ al4,
                                                       int Kp) {
    const int NW = MODE ? 512 : 256;
    __shared__ __align__(16) short As[4096];
    __shared__ __align__(16) unsigned short Cs[2][32][132];
    const int tid = threadIdx.x;
    const int l   = tid & 63;
    const int w   = tid >> 6;
    const int wm  = w >> 1, wn = w & 1;
    const int row0 = blockIdx.y * 128;
    const int col0 = blockIdx.x * 128;
    const int lrow = l & 15;
    const int lq   = l >> 4;
    const int sr = (tid >> 6) * 16 + (tid & 15);
    const int sk = ((tid >> 4) & 3) * 8;

    float4v acc[4][4] = {};

    for (int k0 = 0; k0 < Kp; k0 += 32) {
        short8 a0 = *(const short8*)&A[(size_t)(row0 + sr) * Kp + k0 + sk];
        short8 a1 = *(const short8*)&A[(size_t)(row0 + 64 + sr) * Kp + k0 + sk];
        short8 bfrag[4];
        #pragma unroll
        for (int ct = 0; ct < 4; ++ct) {
            int col = col0 + wn * 64 + ct * 16 + lrow;
            bfrag[ct] = *(const short8*)&Bt[(size_t)col * Kp + k0 + lq * 8];
        }
        __syncthreads();
        *(short8*)&As[tid * 8] = a0;
        *(short8*)&As[(tid + 256) * 8] = a1;
        __syncthreads();
        #pragma unroll
        for (int rt = 0; rt < 4; ++rt) {
            short8 afrag = *(const short8*)&As[(wm * 4 + rt) * 512 + l * 8];
            #pragma unroll
            for (int ct = 0; ct < 4; ++ct)
                acc[rt][ct] = __builtin_amdgcn_mfma_f32_16x16x32_bf16(afrag, bfrag[ct],
                                                                      acc[rt][ct], 0, 0, 0);
        }
    }

    const int colbase = col0 + wn * 64;           // this wave's 64-col span start
    const bool isW = colbase < NW;

    // ---- al_s / al_d reduction (W-part only; plain stores, no atomics)
    if (isW) {
        const int head = (colbase * NHEAD) / NW;
        const int half = MODE ? ((colbase >> 6) & 1) : 0;
        float* als_o = al4 + (half ? 2 * N4 : 0);
        float* ald_o = als_o + N4;
        float as_c[4], ad_c[4];
        #pragma unroll
        for (int ct = 0; ct < 4; ++ct) {
            int col = colbase + ct * 16 + lrow;
            as_c[ct] = asv[col];
            ad_c[ct] = adv[col];
        }
        #pragma unroll
        for (int rt = 0; rt < 4; ++rt) {
            #pragma unroll
            for (int i = 0; i < 4; ++i) {
                int r = row0 + wm * 64 + rt * 16 + lq * 4 + i;
                float fs = 0.f, fd = 0.f;
                #pragma unroll
                for (int ct = 0; ct < 4; ++ct) {
                    float v = acc[rt][ct][i];
                    fs += v * as_c[ct];
                    fd += v * ad_c[ct];
                }
                #pragma unroll
                for (int o2 = 8; o2; o2 >>= 1) {
                    fs += __shfl_xor(fs, o2, 16);
                    fd += __shfl_xor(fd, o2, 16);
                }
                if (lrow == 0 && r < NNODES) {
                    als_o[r * 4 + head] = fs;
                    ald_o[r * 4 + head] = fd;
                }
            }
        }
    }

    // ---- stores
    if (MODE == 1 && col0 >= 512) {
        // fp32 out block (121 real cols): scalar path
        #pragma unroll
        for (int ct = 0; ct < 4; ++ct) {
            int c = colbase + ct * 16 + lrow - 512;
            if (c >= 121) continue;
            float bv = bias[c];
            #pragma unroll
            for (int rt = 0; rt < 4; ++rt) {
                int rbase = row0 + wm * 64 + rt * 16 + lq * 4;
                #pragma unroll
                for (int i = 0; i < 4; ++i) {
                    int r = rbase + i;
                    if (r < NNODES) out[(size_t)r * 121 + c] = acc[rt][ct][i] + bv;
                }
            }
        }
        return;
    }

    // bf16 destination for this block (block-uniform)
    const bool isRb = (MODE == 0) && (col0 >= 256);
    unsigned short* dest = isRb ? Rb : Fb;
    const int ldd = MODE ? 512 : 256;
    const int cold = isRb ? col0 - 256 : col0;
    float badd[4] = {0.f, 0.f, 0.f, 0.f};
    if (isRb) {
        #pragma unroll
        for (int ct = 0; ct < 4; ++ct)
            badd[ct] = bias[col0 - 256 + wn * 64 + ct * 16 + lrow];
    }

    const int rp = tid >> 2, g = rp >> 5, rr = rp & 31, q = tid & 3;
    #pragma unroll
    for (int p = 0; p < 2; ++p) {
        if (p) __syncthreads();
        #pragma unroll
        for (int rt2 = 0; rt2 < 2; ++rt2) {
            int rt = p * 2 + rt2;
            #pragma unroll
            for (int ct = 0; ct < 4; ++ct) {
                int cl = wn * 64 + ct * 16 + lrow;
                #pragma unroll
                for (int i = 0; i < 4; ++i) {
                    int lr = rt2 * 16 + lq * 4 + i;
                    Cs[wm][lr][cl] = f2bf(acc[rt][ct][i] + badd[ct]);
                }
            }
        }
        __syncthreads();
        int grow = row0 + g * 64 + p * 32 + rr;
        if (grow < NNODES) {
            #pragma unroll
            for (int k = 0; k < 4; ++k) {
                ushort8v v = *(const ushort8v*)&Cs[g][rr][q * 32 + 8 * k];
                *(ushort8v*)&dest[(size_t)grow * ldd + cold + q * 32 + 8 * k] = v;
            }
        }
    }
}

// --------------------------------------------------- attn layers 1-2 (C=64, concat)
// wave per node; half-wave (32 lanes) per edge, 2 edges/iter; lane = 8 ch (16B).
__global__ __launch_bounds__(256) void attn64_kernel(const unsigned short* __restrict__ featb,
                                                     const float* __restrict__ al4,
                                                     const int* __restrict__ offs,
                                                     const int* __restrict__ csr,
                                                     const float* __restrict__ p4,
                                                     const unsigned short* __restrict__ Rb,
                                                     unsigned short* __restrict__ outb) {
    int n = blockIdx.x * 4 + (threadIdx.x >> 6);
    int l = threadIdx.x & 63;
    int half = l >> 5, li = l & 31;
    int h = li >> 3;                         // 8 lanes/head, 8 ch/lane
    int beg = n ? offs[n - 1] : 0;
    int end = offs[n];

    float a[8] = {};
    float s = 0.f;
    #pragma unroll 4
    for (int j = beg + half; j < end; j += 2) {
        int sn = csr[j];
        float p = p4[(size_t)j * 4 + h];
        s += p;
        ushort8v f = *(const ushort8v*)&featb[(size_t)sn * 256 + 8 * li];
        #pragma unroll
        for (int i = 0; i < 8; ++i) a[i] += p * bf2f(f[i]);
    }
    s += __shfl_xor(s, 32, 64);
    #pragma unroll
    for (int i = 0; i < 8; ++i) a[i] += __shfl_xor(a[i], 32, 64);

    // self-loop
    float lg = al4[n * 4 + h] + al4[2 * N4 + n * 4 + h]
             + al4[N4 + n * 4 + h] + al4[3 * N4 + n * 4 + h];
    float p0 = __expf(lrelu(lg));
    s += p0;
    {
        ushort8v f = *(const ushort8v*)&featb[(size_t)n * 256 + 8 * li];
        #pragma unroll
        for (int i = 0; i < 8; ++i) a[i] += p0 * bf2f(f[i]);
    }
    if (half == 0) {
        float inv = 1.f / s;
        ushort8v r = *(const ushort8v*)&Rb[(size_t)n * 256 + 8 * li];
        ushort8v o;
        #pragma unroll
        for (int i = 0; i < 8; ++i) o[i] = f2bf(fmaxf(bf2f(r[i]) + a[i] * inv, 0.f));
        *(ushort8v*)&outb[(size_t)n * 256 + 8 * li] = o;
    }
}

// --------------------------------------------------- attn layer 3 (fp8 feat, mean)
// wave per node; half-wave per edge (16B = 16 fp8/lane); HW fp8->f32 decode.
__global__ __launch_bounds__(256) void attn121_kernel(const unsigned int* __restrict__ F8,
                                                      const float* __restrict__ al4,
                                                      const int* __restrict__ offs,
                                                      const int* __restrict__ csr,
                                                      const float* __restrict__ p4,
                                                      float* __restrict__ out) {
    int n = blockIdx.x * 4 + (threadIdx.x >> 6);
    int l = threadIdx.x & 63;
    int half = l >> 5, li = l & 31;
    int h = li >> 3;                         // 8 lanes/head, 16 ch/lane (128-pad head)
    int beg = n ? offs[n - 1] : 0;
    int end = offs[n];

    float a[16] = {};
    float s = 0.f;
    #pragma unroll 2
    for (int j = beg + half; j < end; j += 2) {
        int sn = csr[j];
        float p = p4[(size_t)j * 4 + h];
        s += p;
        uint4v u = *(const uint4v*)&F8[(size_t)sn * 128 + 4 * li];
        #pragma unroll
        for (int k = 0; k < 4; ++k) {
            float2v lo = __builtin_amdgcn_cvt_pk_f32_fp8(u[k], false);
            float2v hi = __builtin_amdgcn_cvt_pk_f32_fp8(u[k], true);
            a[4 * k + 0] += p * lo.x; a[4 * k + 1] += p * lo.y;
            a[4 * k + 2] += p * hi.x; a[4 * k + 3] += p * hi.y;
        }
    }
    s += __shfl_xor(s, 32, 64);
    #pragma unroll
    for (int i = 0; i < 16; ++i) a[i] += __shfl_xor(a[i], 32, 64);

    // self-loop
    float lg = al4[n * 4 + h] + al4[2 * N4 + n * 4 + h]
             + al4[N4 + n * 4 + h] + al4[3 * N4 + n * 4 + h];
    float p0 = __expf(lrelu(lg));
    s += p0;
    {
        uint4v u = *(const uint4v*)&F8[(size_t)n * 128 + 4 * li];
        #pragma unroll
        for (int k = 0; k < 4; ++k) {
            float2v lo = __builtin_amdgcn_cvt_pk_f32_fp8(u[k], false);
            float2v hi = __builtin_amdgcn_cvt_pk_f32_fp8(u[k], true);
            a[4 * k + 0] += p0 * lo.x; a[4 * k + 1] += p0 * lo.y;
            a[4 * k + 2] += p0 * hi.x; a[4 * k + 3] += p0 * hi.y;
        }
    }
    float inv = 0.25f / s;                 // mean over heads
    #pragma unroll
    for (int i = 0; i < 16; ++i) {
        a[i] *= inv;
        a[i] += __shfl_xor(a[i], 8, 64);   // sum 4 head groups (lanes li^8, li^16)
        a[i] += __shfl_xor(a[i], 16, 64);
    }
    if (l < 8) {                           // half 0, head 0 lanes hold channel sums
        #pragma unroll
        for (int i = 0; i < 16; ++i) {
            int c = 16 * l + i;
            if (c < 121) out[(size_t)n * 121 + c] += a[i];
        }
    }
}

// ---------------------------------------------------------------- launch
extern "C" void kernel_launch(void* const* d_in, const int* in_sizes, int n_in,
                              void* d_out, int out_size, void* d_ws, size_t ws_size,
                              hipStream_t stream) {
    const float* x   = (const float*)d_in[0];
    const int* ei    = (const int*)d_in[1];
    const float* W1  = (const float*)d_in[2];
    const float* a1s = (const float*)d_in[3];
    const float* a1d = (const float*)d_in[4];
    const float* Wr1 = (const float*)d_in[5];
    const float* b1  = (const float*)d_in[6];
    const float* W2  = (const float*)d_in[7];
    const float* a2s = (const float*)d_in[8];
    const float* a2d = (const float*)d_in[9];
    const float* Wr2 = (const float*)d_in[10];
    const float* b2  = (const float*)d_in[11];
    const float* W3  = (const float*)d_in[12];
    const float* a3s = (const float*)d_in[13];
    const float* a3d = (const float*)d_in[14];
    const float* Wr3 = (const float*)d_in[15];
    const float* b3  = (const float*)d_in[16];
    float* out = (float*)d_out;

    const int* e_src = ei;
    const int* e_dst = ei + NEDGES;

    char* ws = (char*)d_ws;
    size_t off = 0;
    auto carve = [&](size_t bytes) { void* p = ws + off; off += (bytes + 255) & ~255ull; return p; };
    unsigned short* Fb = (unsigned short*)carve((size_t)MPAD * 512 * 2);
    unsigned short* Rb = (unsigned short*)carve((size_t)MPAD * 256 * 2);
    unsigned short* Hb = (unsigned short*)carve((size_t)MPAD * 256 * 2);
    unsigned int* F8 = (unsigned int*)carve((size_t)NNODES * 128 * 4);
    short* xb   = (short*)carve((size_t)MPAD * 64 * 2);
    short* wc1  = (short*)carve((size_t)512 * 64 * 2);
    short* wc2  = (short*)carve((size_t)512 * 256 * 2);
    short* wc3  = (short*)carve((size_t)640 * 256 * 2);
    float* a3sp = (float*)carve(512 * 4);
    float* a3dp = (float*)carve(512 * 4);
    float* al4  = (float*)carve((size_t)4 * N4 * 4);   // [als0|ald0|als1|ald1]
    float* p4   = (float*)carve((size_t)NEDGES * 4 * 4);
    int* csr_src = (int*)carve((size_t)NEDGES * 4);
    int* csr_dst = (int*)carve((size_t)NEDGES * 4);
    int* offsets = (int*)carve(((size_t)NNODES + 4) * 4);
    int* counts  = (int*)carve((size_t)NNODES * 4);
    int* partials = (int*)carve(256 * 4);
    int* pexcl    = (int*)carve(256 * 4);

    const int EB = (NEDGES + 255) / 256;
    dim3 blk(256);

    // conversions (3 launches)
    convert_x<<<(MPAD * 64 + 255) / 256, blk, 0, stream>>>(x, xb);
    convert_pack1<<<(163840 + 255) / 256, blk, 0, stream>>>(W1, Wr1, W2, Wr2, wc1, wc2);
    convert_pack2<<<(164864 + 255) / 256, blk, 0, stream>>>(W3, Wr3, a3s, a3d, wc3, a3sp, a3dp);

    // zero half-1 al planes once (layers 1-2 write half 0 only; layer 3 writes both)
    hipMemsetAsync(al4 + 2 * N4, 0, (size_t)2 * N4 * 4, stream);

    // CSR by dst (parallel scan; scatter mutates offsets into end-positions)
    hipMemsetAsync(counts, 0, NNODES * 4, stream);
    hist_kernel<<<EB, blk, 0, stream>>>(e_dst, counts, NEDGES);
    scan_local<<<SCANB, blk, 0, stream>>>(counts, offsets, partials);
    scan_partials<<<1, blk, 0, stream>>>(partials, pexcl);
    scan_carry<<<SCANB, blk, 0, stream>>>(offsets, pexcl);
    scatter_kernel<<<EB, blk, 0, stream>>>(e_src, e_dst, offsets, csr_src, csr_dst, NEDGES);

    // ---- layer 1 (K=64)
    mfma_gemm_fused<0><<<dim3(4, 313), blk, 0, stream>>>(xb, wc1, b1, a1s, a1d,
                                                         Fb, Rb, nullptr, al4, 64);
    edge_p<<<EB, blk, 0, stream>>>(al4, csr_src, csr_dst, p4, NEDGES);
    attn64_kernel<<<NNODES / 4, blk, 0, stream>>>(Fb, al4, offsets, csr_src, p4, Rb, Hb);

    // ---- layer 2 (K=256)
    mfma_gemm_fused<0><<<dim3(4, 313), blk, 0, stream>>>((short*)Hb, wc2, b2, a2s, a2d,
                                                         Fb, Rb, nullptr, al4, 256);
    edge_p<<<EB, blk, 0, stream>>>(al4, csr_src, csr_dst, p4, NEDGES);
    attn64_kernel<<<NNODES / 4, blk, 0, stream>>>(Fb, al4, offsets, csr_src, p4, Rb, Hb);

    // ---- layer 3 (K=256, N=640)
    mfma_gemm_fused<1><<<dim3(5, 313), blk, 0, stream>>>((short*)Hb, wc3, b3, a3sp, a3dp,
                                                         Fb, nullptr, out, al4, 256);
    convert_f8<<<(NNODES * 128 + 255) / 256, blk, 0, stream>>>(Fb, F8);
    edge_p<<<EB, blk, 0, stream>>>(al4, csr_src, csr_dst, p4, NEDGES);
    attn121_kernel<<<NNODES / 4, blk, 0, stream>>>(F8, al4, offsets, csr_src, p4, out);
}